// Round 1
// baseline (888.053 us; speedup 1.0000x reference)
//
#include <hip/hip_runtime.h>
#include <math.h>

#define B_  16
#define H_  8
#define L_  512
#define DM_ 512
#define DK_ 64

// ---------------------------------------------------------------------------
// GEMM:  Y[M,N] = X[M,K] @ W[N,K]^T + bias[N]   (torch Linear convention)
// 64x64 tile per block, 256 threads, 4x4 register blocking, K staged
// transposed in LDS so the inner loop is 2x ds_read_b128 + 16 FMA per k.
// ---------------------------------------------------------------------------
__global__ __launch_bounds__(256) void gemm_nt_bias(
    const float* __restrict__ X, const float* __restrict__ W,
    const float* __restrict__ bias, float* __restrict__ Y,
    int M, int N, int K)
{
    __shared__ float Xt[32][68];   // [k][row]  (pitch 68 floats: 16B aligned, conflict-free)
    __shared__ float Wt[32][68];   // [k][col]

    const int tid = threadIdx.x;
    const int tx = tid & 15;       // output col group
    const int ty = tid >> 4;       // output row group
    const int row0 = blockIdx.y * 64;
    const int col0 = blockIdx.x * 64;

    float acc[4][4] = {};

    for (int k0 = 0; k0 < K; k0 += 32) {
        // stage 64x32 of X and W, transposed into LDS
        #pragma unroll
        for (int i = 0; i < 2; ++i) {
            int f = tid + i * 256;          // 0..511
            int r = f >> 3;                 // 0..63
            int q = f & 7;                  // float4 index along k
            float4 xv = *(const float4*)&X[(size_t)(row0 + r) * K + k0 + q * 4];
            float4 wv = *(const float4*)&W[(size_t)(col0 + r) * K + k0 + q * 4];
            Xt[q * 4 + 0][r] = xv.x; Xt[q * 4 + 1][r] = xv.y;
            Xt[q * 4 + 2][r] = xv.z; Xt[q * 4 + 3][r] = xv.w;
            Wt[q * 4 + 0][r] = wv.x; Wt[q * 4 + 1][r] = wv.y;
            Wt[q * 4 + 2][r] = wv.z; Wt[q * 4 + 3][r] = wv.w;
        }
        __syncthreads();

        #pragma unroll
        for (int kk = 0; kk < 32; ++kk) {
            float4 a4 = *(const float4*)&Xt[kk][ty * 4];
            float4 b4 = *(const float4*)&Wt[kk][tx * 4];
            float a[4] = {a4.x, a4.y, a4.z, a4.w};
            float b[4] = {b4.x, b4.y, b4.z, b4.w};
            #pragma unroll
            for (int i = 0; i < 4; ++i)
                #pragma unroll
                for (int j = 0; j < 4; ++j)
                    acc[i][j] = fmaf(a[i], b[j], acc[i][j]);
        }
        __syncthreads();
    }

    float4 bv4 = *(const float4*)&bias[col0 + tx * 4];
    #pragma unroll
    for (int i = 0; i < 4; ++i) {
        float4 o;
        o.x = acc[i][0] + bv4.x;
        o.y = acc[i][1] + bv4.y;
        o.z = acc[i][2] + bv4.z;
        o.w = acc[i][3] + bv4.w;
        *(float4*)&Y[(size_t)(row0 + ty * 4 + i) * N + col0 + tx * 4] = o;
    }
}

// ---------------------------------------------------------------------------
// gamma: g = q_row @ Wg^T + bg  (per (b,h,l));  qp = (|g|+1)^-2
// 16 lanes per row (coalesced 256B row read), shfl reduce within group.
// QP layout: [B][H][L][2]
// ---------------------------------------------------------------------------
__global__ __launch_bounds__(256) void gamma_kernel(
    const float* __restrict__ Q, const float* __restrict__ Wg,
    const float* __restrict__ bg, float* __restrict__ QP)
{
    __shared__ float wg[128];
    const int tid = threadIdx.x;
    if (tid < 128) wg[tid] = Wg[tid];
    __syncthreads();

    const int grp = tid >> 4;   // 16 groups of 16 lanes
    const int gl  = tid & 15;
    const int idx = blockIdx.x * 16 + grp;          // ((b*H + h)*L + l)
    const int b = idx >> 12;                        // H*L = 4096
    const int h = (idx >> 9) & 7;
    const int l = idx & 511;

    const float* qrow = Q + ((size_t)(b * L_ + l) * DM_ + h * DK_);
    float4 q4 = *(const float4*)&qrow[gl * 4];

    float g0 = q4.x * wg[gl * 4 + 0] + q4.y * wg[gl * 4 + 1]
             + q4.z * wg[gl * 4 + 2] + q4.w * wg[gl * 4 + 3];
    float g1 = q4.x * wg[64 + gl * 4 + 0] + q4.y * wg[64 + gl * 4 + 1]
             + q4.z * wg[64 + gl * 4 + 2] + q4.w * wg[64 + gl * 4 + 3];
    #pragma unroll
    for (int off = 8; off; off >>= 1) {
        g0 += __shfl_xor(g0, off);
        g1 += __shfl_xor(g1, off);
    }
    if (gl == 0) {
        g0 += bg[0];
        g1 += bg[1];
        float t0 = fabsf(g0) + 1.f;
        float t1 = fabsf(g1) + 1.f;
        QP[(size_t)idx * 2 + 0] = 1.f / (t0 * t0);
        QP[(size_t)idx * 2 + 1] = 1.f / (t1 * t1);
    }
}

// ---------------------------------------------------------------------------
// Fused attention.  Key identity: softmax(s)/rowmax(softmax(s)) == exp(s - rowmax(s)).
//   p_ij  = sg*exp(s_ij - m_i) + (1-sg)*exp(qp_sel * (-(i-j)^2/2))
//   out_i = sum_j p_ij v_j / (sum_j p_ij + 1e-9)
// Block: 16 q-rows of one (b,h).  4 waves x 4 rows.  Online max on the score
// branch only (adjacency branch is max-independent): separate accumulators.
// ---------------------------------------------------------------------------
__global__ __launch_bounds__(256) void attn_kernel(
    const float* __restrict__ Q, const float* __restrict__ K,
    const float* __restrict__ V, const float* __restrict__ QP,
    const float* __restrict__ lam1, float* __restrict__ ATT)
{
    __shared__ float  qs[16][64];
    __shared__ float  qpl[16][2];
    __shared__ float4 Kv4[16][65];    // [dq][c] : K[c0+c][dq*4..+3], padded
    __shared__ float  Vs[64][68];     // [c][d], pitch 68 (aligned, conflict-free)
    __shared__ float  pbuf[4][4][2][64];  // [wave][row][{p,a}][col]

    const int tid  = threadIdx.x;
    const int w    = tid >> 6;
    const int lane = tid & 63;
    const int l0   = blockIdx.x * 16;
    const int h    = blockIdx.y;
    const int b    = blockIdx.z;
    const float sg  = 1.f / (1.f + __expf(-lam1[0]));
    const float osg = 1.f - sg;

    // stage the 16 q rows + qp pairs
    {
        int r = tid >> 4, dq = tid & 15;
        *(float4*)&qs[r][dq * 4] =
            *(const float4*)&Q[(size_t)(b * L_ + l0 + r) * DM_ + h * DK_ + dq * 4];
    }
    if (tid < 32) {
        int r = tid >> 1, c = tid & 1;
        qpl[r][c] = QP[((size_t)((b * H_ + h) * L_) + l0 + r) * 2 + c];
    }
    __syncthreads();

    const int lrow = l0 + w * 4;   // this wave's first row
    float m[4], sumS[4], sumA[4], accS[4], accA[4];
    float qp0[4], qp1[4];
    #pragma unroll
    for (int r = 0; r < 4; ++r) {
        m[r] = -1e38f; sumS[r] = 0.f; sumA[r] = 0.f; accS[r] = 0.f; accA[r] = 0.f;
        qp0[r] = qpl[w * 4 + r][0];
        qp1[r] = qpl[w * 4 + r][1];
    }

    for (int t = 0; t < 8; ++t) {
        const int c0 = t * 64;
        // stage K,V tile (64 cols x 64 dims)
        #pragma unroll
        for (int i = 0; i < 4; ++i) {
            int f = tid + i * 256;         // 0..1023
            int r = f >> 4;                // tile column (= K/V row)
            int dq = f & 15;
            size_t gbase = (size_t)(b * L_ + c0 + r) * DM_ + h * DK_ + dq * 4;
            Kv4[dq][r] = *(const float4*)&K[gbase];
            *(float4*)&Vs[r][dq * 4] = *(const float4*)&V[gbase];
        }
        __syncthreads();

        // scores: lane holds column c0+lane for the wave's 4 rows
        float s[4] = {0.f, 0.f, 0.f, 0.f};
        #pragma unroll
        for (int dq = 0; dq < 16; ++dq) {
            float4 k4 = Kv4[dq][lane];
            #pragma unroll
            for (int r = 0; r < 4; ++r) {
                float4 q4 = *(const float4*)&qs[w * 4 + r][dq * 4];
                s[r] = fmaf(q4.x, k4.x, s[r]);
                s[r] = fmaf(q4.y, k4.y, s[r]);
                s[r] = fmaf(q4.z, k4.z, s[r]);
                s[r] = fmaf(q4.w, k4.w, s[r]);
            }
        }

        const int jc = c0 + lane;
        #pragma unroll
        for (int r = 0; r < 4; ++r) {
            float tm = s[r];
            #pragma unroll
            for (int off = 32; off; off >>= 1) tm = fmaxf(tm, __shfl_xor(tm, off));
            float nm = fmaxf(m[r], tm);
            float sc = __expf(m[r] - nm);     // 1 when max unchanged; 0 on first tile
            m[r] = nm;
            accS[r] *= sc;
            sumS[r] *= sc;
            float p = __expf(s[r] - nm);
            sumS[r] += p;                     // per-lane partial, reduced at the end
            int   li   = lrow + r;
            float diff = (float)(li - jc);
            float qsel = (jc < li) ? qp1[r] : qp0[r];
            float a = __expf(qsel * (-0.5f * diff * diff));
            sumA[r] += a;
            pbuf[w][r][0][lane] = p;
            pbuf[w][r][1][lane] = a;
        }
        __syncthreads();   // pbuf visibility (cross-lane through LDS)

        // PV: lane holds output dim d = lane
        #pragma unroll
        for (int c4 = 0; c4 < 16; ++c4) {
            float4 pv0 = *(const float4*)&pbuf[w][0][0][c4 * 4];
            float4 pv1 = *(const float4*)&pbuf[w][1][0][c4 * 4];
            float4 pv2 = *(const float4*)&pbuf[w][2][0][c4 * 4];
            float4 pv3 = *(const float4*)&pbuf[w][3][0][c4 * 4];
            float4 av0 = *(const float4*)&pbuf[w][0][1][c4 * 4];
            float4 av1 = *(const float4*)&pbuf[w][1][1][c4 * 4];
            float4 av2 = *(const float4*)&pbuf[w][2][1][c4 * 4];
            float4 av3 = *(const float4*)&pbuf[w][3][1][c4 * 4];
            float v0 = Vs[c4 * 4 + 0][lane];
            float v1 = Vs[c4 * 4 + 1][lane];
            float v2 = Vs[c4 * 4 + 2][lane];
            float v3 = Vs[c4 * 4 + 3][lane];
            accS[0] += pv0.x * v0 + pv0.y * v1 + pv0.z * v2 + pv0.w * v3;
            accS[1] += pv1.x * v0 + pv1.y * v1 + pv1.z * v2 + pv1.w * v3;
            accS[2] += pv2.x * v0 + pv2.y * v1 + pv2.z * v2 + pv2.w * v3;
            accS[3] += pv3.x * v0 + pv3.y * v1 + pv3.z * v2 + pv3.w * v3;
            accA[0] += av0.x * v0 + av0.y * v1 + av0.z * v2 + av0.w * v3;
            accA[1] += av1.x * v0 + av1.y * v1 + av1.z * v2 + av1.w * v3;
            accA[2] += av2.x * v0 + av2.y * v1 + av2.z * v2 + av2.w * v3;
            accA[3] += av3.x * v0 + av3.y * v1 + av3.z * v2 + av3.w * v3;
        }
        __syncthreads();   // before next tile overwrites Kv4/Vs
    }

    #pragma unroll
    for (int r = 0; r < 4; ++r) {
        float S = sumS[r], A = sumA[r];
        #pragma unroll
        for (int off = 32; off; off >>= 1) {
            S += __shfl_xor(S, off);
            A += __shfl_xor(A, off);
        }
        float denom = sg * S + osg * A + 1e-9f;
        float res = (sg * accS[r] + osg * accA[r]) / denom;
        ATT[(size_t)(b * L_ + lrow + r) * DM_ + h * DK_ + lane] = res;
    }
}

// ---------------------------------------------------------------------------
extern "C" void kernel_launch(void* const* d_in, const int* in_sizes, int n_in,
                              void* d_out, int out_size, void* d_ws, size_t ws_size,
                              hipStream_t stream)
{
    (void)in_sizes; (void)n_in; (void)out_size; (void)ws_size;
    const float* query = (const float*)d_in[0];
    const float* key   = (const float*)d_in[1];
    const float* value = (const float*)d_in[2];
    const float* Wq = (const float*)d_in[3];  const float* bq = (const float*)d_in[4];
    const float* Wk = (const float*)d_in[5];  const float* bk = (const float*)d_in[6];
    const float* Wv = (const float*)d_in[7];  const float* bv = (const float*)d_in[8];
    const float* Wg = (const float*)d_in[9];  const float* bg = (const float*)d_in[10];
    const float* lam1 = (const float*)d_in[11];
    const float* Wo = (const float*)d_in[12]; const float* bo = (const float*)d_in[13];
    float* out = (float*)d_out;

    float* ws = (float*)d_ws;
    const size_t NROW = (size_t)B_ * L_;          // 8192
    float* Kb  = ws;
    float* Vb  = ws + NROW * DM_;
    float* Qb  = ws + 2 * NROW * DM_;
    float* QPb = ws + 3 * NROW * DM_;
    float* ATTb = Qb;   // safe alias: attention reads exactly the q elements it later writes

    dim3 gg(DM_ / 64, NROW / 64);                 // (8, 128)
    gemm_nt_bias<<<gg, 256, 0, stream>>>(query, Wq, bq, Qb, (int)NROW, DM_, DM_);
    gemm_nt_bias<<<gg, 256, 0, stream>>>(key,   Wk, bk, Kb, (int)NROW, DM_, DM_);
    gemm_nt_bias<<<gg, 256, 0, stream>>>(value, Wv, bv, Vb, (int)NROW, DM_, DM_);

    gamma_kernel<<<(B_ * H_ * L_) / 16, 256, 0, stream>>>(Qb, Wg, bg, QPb);

    dim3 ga(L_ / 16, H_, B_);
    attn_kernel<<<ga, 256, 0, stream>>>(Qb, Kb, Vb, QPb, lam1, ATTb);

    gemm_nt_bias<<<gg, 256, 0, stream>>>(ATTb, Wo, bo, out, (int)NROW, DM_, DM_);
}

// Round 2
// 331.572 us; speedup vs baseline: 2.6783x; 2.6783x over previous
//
#include <hip/hip_runtime.h>
#include <math.h>

#define B_  16
#define H_  8
#define L_  512
#define DM_ 512
#define DK_ 64
#define LOG2E_ 1.44269504088896340736f

typedef __attribute__((ext_vector_type(8)))  short bf16x8;
typedef __attribute__((ext_vector_type(16))) float f32x16;

__device__ __forceinline__ unsigned short f2bf(float x) {
    union { float f; unsigned u; } v; v.f = x;
    unsigned r = v.u + 0x7FFFu + ((v.u >> 16) & 1u);
    return (unsigned short)(r >> 16);
}
__device__ __forceinline__ float bf2f(unsigned short b) {
    union { unsigned u; float f; } v; v.u = ((unsigned)b) << 16;
    return v.f;
}

// ---------------------------------------------------------------------------
// GEMM:  Y[M,N] = X[M,K] @ W[N,K]^T + bias[N]   (unchanged from round 0)
// ---------------------------------------------------------------------------
__global__ __launch_bounds__(256) void gemm_nt_bias(
    const float* __restrict__ X, const float* __restrict__ W,
    const float* __restrict__ bias, float* __restrict__ Y,
    int M, int N, int K)
{
    __shared__ float Xt[32][68];
    __shared__ float Wt[32][68];

    const int tid = threadIdx.x;
    const int tx = tid & 15;
    const int ty = tid >> 4;
    const int row0 = blockIdx.y * 64;
    const int col0 = blockIdx.x * 64;

    float acc[4][4] = {};

    for (int k0 = 0; k0 < K; k0 += 32) {
        #pragma unroll
        for (int i = 0; i < 2; ++i) {
            int f = tid + i * 256;
            int r = f >> 3;
            int qq = f & 7;
            float4 xv = *(const float4*)&X[(size_t)(row0 + r) * K + k0 + qq * 4];
            float4 wv = *(const float4*)&W[(size_t)(col0 + r) * K + k0 + qq * 4];
            Xt[qq * 4 + 0][r] = xv.x; Xt[qq * 4 + 1][r] = xv.y;
            Xt[qq * 4 + 2][r] = xv.z; Xt[qq * 4 + 3][r] = xv.w;
            Wt[qq * 4 + 0][r] = wv.x; Wt[qq * 4 + 1][r] = wv.y;
            Wt[qq * 4 + 2][r] = wv.z; Wt[qq * 4 + 3][r] = wv.w;
        }
        __syncthreads();

        #pragma unroll
        for (int kk = 0; kk < 32; ++kk) {
            float4 a4 = *(const float4*)&Xt[kk][ty * 4];
            float4 b4 = *(const float4*)&Wt[kk][tx * 4];
            float a[4] = {a4.x, a4.y, a4.z, a4.w};
            float bb[4] = {b4.x, b4.y, b4.z, b4.w};
            #pragma unroll
            for (int i = 0; i < 4; ++i)
                #pragma unroll
                for (int j = 0; j < 4; ++j)
                    acc[i][j] = fmaf(a[i], bb[j], acc[i][j]);
        }
        __syncthreads();
    }

    float4 bv4 = *(const float4*)&bias[col0 + tx * 4];
    #pragma unroll
    for (int i = 0; i < 4; ++i) {
        float4 o;
        o.x = acc[i][0] + bv4.x;
        o.y = acc[i][1] + bv4.y;
        o.z = acc[i][2] + bv4.z;
        o.w = acc[i][3] + bv4.w;
        *(float4*)&Y[(size_t)(row0 + ty * 4 + i) * N + col0 + tx * 4] = o;
    }
}

// ---------------------------------------------------------------------------
// gamma: g = q_row @ Wg^T + bg;  qp = (|g|+1)^-2    (unchanged)
// ---------------------------------------------------------------------------
__global__ __launch_bounds__(256) void gamma_kernel(
    const float* __restrict__ Q, const float* __restrict__ Wg,
    const float* __restrict__ bg, float* __restrict__ QP)
{
    __shared__ float wg[128];
    const int tid = threadIdx.x;
    if (tid < 128) wg[tid] = Wg[tid];
    __syncthreads();

    const int grp = tid >> 4;
    const int gl  = tid & 15;
    const int idx = blockIdx.x * 16 + grp;
    const int b = idx >> 12;
    const int h = (idx >> 9) & 7;
    const int l = idx & 511;

    const float* qrow = Q + ((size_t)(b * L_ + l) * DM_ + h * DK_);
    float4 q4 = *(const float4*)&qrow[gl * 4];

    float g0 = q4.x * wg[gl * 4 + 0] + q4.y * wg[gl * 4 + 1]
             + q4.z * wg[gl * 4 + 2] + q4.w * wg[gl * 4 + 3];
    float g1 = q4.x * wg[64 + gl * 4 + 0] + q4.y * wg[64 + gl * 4 + 1]
             + q4.z * wg[64 + gl * 4 + 2] + q4.w * wg[64 + gl * 4 + 3];
    #pragma unroll
    for (int off = 8; off; off >>= 1) {
        g0 += __shfl_xor(g0, off);
        g1 += __shfl_xor(g1, off);
    }
    if (gl == 0) {
        g0 += bg[0];
        g1 += bg[1];
        float t0 = fabsf(g0) + 1.f;
        float t1 = fabsf(g1) + 1.f;
        QP[(size_t)idx * 2 + 0] = 1.f / (t0 * t0);
        QP[(size_t)idx * 2 + 1] = 1.f / (t1 * t1);
    }
}

// ---------------------------------------------------------------------------
// MFMA flash attention.
//   p  = exp2(s*log2e - m2);  a = exp2(-0.72135*qp_sel*d^2)
//   out = (sg*accS + (1-sg)*accA) / (sg*sumS + (1-sg)*sumA + 1e-9)
// 4 waves x 32 q-rows = 128 q-rows/block; KV tiles of 64.
// S^T = mfma(Kfrag, Qfrag): lane owns q-row (lane&31) -> cheap row ops.
// Split-bf16 (hi+lo) QK^T for accuracy; PV plain bf16 via LDS P-bounce.
// ---------------------------------------------------------------------------
__global__ __launch_bounds__(256) void attn_kernel(
    const float* __restrict__ Q, const float* __restrict__ K,
    const float* __restrict__ V, const float* __restrict__ QP,
    const float* __restrict__ lam1, float* __restrict__ ATT)
{
    __shared__ short Kh[64][72];
    __shared__ short Kl[64][72];
    __shared__ short Vt[64][72];      // V^T: [d][c]
    __shared__ short PA[4][32][72];   // per-wave P bounce: [q][k]
    __shared__ float scb[4][32];

    const int tid  = threadIdx.x;
    const int w    = tid >> 6;
    const int lane = tid & 63;
    const int lq   = lane & 31;
    const int half = lane >> 5;
    const int h    = blockIdx.y;
    const int b    = blockIdx.z;
    const int q0w  = blockIdx.x * 128 + w * 32;
    const int q    = q0w + lq;

    const float sg  = 1.f / (1.f + __expf(-lam1[0]));
    const float osg = 1.f - sg;

    // Q fragments (B-operand), scaled by log2e, split hi/lo bf16
    bf16x8 qh[4], ql[4];
    {
        const float* qrow = Q + ((size_t)(b * L_ + q) * DM_ + h * DK_);
        #pragma unroll
        for (int db = 0; db < 4; ++db) {
            const int d0 = db * 16 + 8 * half;
            float4 x0 = *(const float4*)&qrow[d0];
            float4 x1 = *(const float4*)&qrow[d0 + 4];
            float xs[8] = {x0.x, x0.y, x0.z, x0.w, x1.x, x1.y, x1.z, x1.w};
            #pragma unroll
            for (int j = 0; j < 8; ++j) {
                float xx = xs[j] * LOG2E_;
                unsigned short hb = f2bf(xx);
                qh[db][j] = (short)hb;
                ql[db][j] = (short)f2bf(xx - bf2f(hb));
            }
        }
    }

    // per-row adjacency coefficients (lane owns q-row lq)
    float A0, A1, qpw;
    {
        const float* qpp = QP + ((size_t)((b * H_ + h) * L_) + q) * 2;
        float p0 = qpp[0], p1 = qpp[1];
        A0 = -0.72134752f * p0;     // c >= q  (triu / qp[...,0])
        A1 = -0.72134752f * p1;     // c <  q  (tril / qp[...,1])
        float mn = 0.72134752f * fminf(p0, p1);
        #pragma unroll
        for (int off = 1; off < 64; off <<= 1) mn = fminf(mn, __shfl_xor(mn, off));
        qpw = mn;
    }

    f32x16 aS0, aS1, aA0, aA1;
    #pragma unroll
    for (int i = 0; i < 16; ++i) { aS0[i] = 0.f; aS1[i] = 0.f; aA0[i] = 0.f; aA1[i] = 0.f; }
    float m2 = -3.0e38f, sumS = 0.f, sumA = 0.f;

    for (int t = 0; t < 8; ++t) {
        const int c0 = t * 64;
        __syncthreads();
        // stage K (hi/lo split) and V^T, fp32 -> bf16
        #pragma unroll
        for (int i = 0; i < 4; ++i) {
            int task = tid + i * 256;
            int c = task >> 4, f4 = task & 15;
            size_t gb = (size_t)(b * L_ + c0 + c) * DM_ + h * DK_ + f4 * 4;
            float4 kx = *(const float4*)&K[gb];
            float4 vx = *(const float4*)&V[gb];
            unsigned kh0 = f2bf(kx.x), kh1 = f2bf(kx.y), kh2 = f2bf(kx.z), kh3 = f2bf(kx.w);
            unsigned kl0 = f2bf(kx.x - bf2f((unsigned short)kh0));
            unsigned kl1 = f2bf(kx.y - bf2f((unsigned short)kh1));
            unsigned kl2 = f2bf(kx.z - bf2f((unsigned short)kh2));
            unsigned kl3 = f2bf(kx.w - bf2f((unsigned short)kh3));
            uint2 hv, lv;
            hv.x = kh0 | (kh1 << 16);  hv.y = kh2 | (kh3 << 16);
            lv.x = kl0 | (kl1 << 16);  lv.y = kl2 | (kl3 << 16);
            *(uint2*)&Kh[c][f4 * 4] = hv;
            *(uint2*)&Kl[c][f4 * 4] = lv;
            Vt[f4 * 4 + 0][c] = (short)f2bf(vx.x);
            Vt[f4 * 4 + 1][c] = (short)f2bf(vx.y);
            Vt[f4 * 4 + 2][c] = (short)f2bf(vx.z);
            Vt[f4 * 4 + 3][c] = (short)f2bf(vx.w);
        }
        __syncthreads();

        // S^T = K . Q^T  (3-term bf16 split), two 32-col subtiles
        f32x16 s2a, s2b;
        #pragma unroll
        for (int i = 0; i < 16; ++i) { s2a[i] = 0.f; s2b[i] = 0.f; }
        #pragma unroll
        for (int db = 0; db < 4; ++db) {
            const int dof = db * 16 + 8 * half;
            bf16x8 kha = *(const bf16x8*)&Kh[lq][dof];
            bf16x8 kla = *(const bf16x8*)&Kl[lq][dof];
            bf16x8 khb = *(const bf16x8*)&Kh[32 + lq][dof];
            bf16x8 klb = *(const bf16x8*)&Kl[32 + lq][dof];
            s2a = __builtin_amdgcn_mfma_f32_32x32x16_bf16(kha, qh[db], s2a, 0, 0, 0);
            s2a = __builtin_amdgcn_mfma_f32_32x32x16_bf16(kha, ql[db], s2a, 0, 0, 0);
            s2a = __builtin_amdgcn_mfma_f32_32x32x16_bf16(kla, qh[db], s2a, 0, 0, 0);
            s2b = __builtin_amdgcn_mfma_f32_32x32x16_bf16(khb, qh[db], s2b, 0, 0, 0);
            s2b = __builtin_amdgcn_mfma_f32_32x32x16_bf16(khb, ql[db], s2b, 0, 0, 0);
            s2b = __builtin_amdgcn_mfma_f32_32x32x16_bf16(klb, qh[db], s2b, 0, 0, 0);
        }

        // online max (lane owns q-row; halves hold complementary k's)
        float tm = s2a[0];
        #pragma unroll
        for (int i = 1; i < 16; ++i) tm = fmaxf(tm, s2a[i]);
        #pragma unroll
        for (int i = 0; i < 16; ++i) tm = fmaxf(tm, s2b[i]);
        tm = fmaxf(tm, __shfl_xor(tm, 32));
        float nm = fmaxf(m2, tm);
        float sc = exp2f(m2 - nm);
        m2 = nm;
        sumS *= sc;
        if (lane < 32) scb[w][lq] = sc;
        #pragma unroll
        for (int r = 0; r < 16; ++r) {
            float s_ = scb[w][(r & 3) + 8 * (r >> 2) + 4 * half];
            aS0[r] *= s_;
            aS1[r] *= s_;
        }

        // p = exp2(s2 - nm); pack to bf16, bounce through PA
        #pragma unroll
        for (int r = 0; r < 16; r += 2) {
            int koff = (r & 3) + 8 * (r >> 2) + 4 * half;
            float p0 = exp2f(s2a[r] - nm), p1 = exp2f(s2a[r + 1] - nm);
            sumS += p0 + p1;
            *(unsigned*)&PA[w][lq][koff] = (unsigned)f2bf(p0) | ((unsigned)f2bf(p1) << 16);
            float p2 = exp2f(s2b[r] - nm), p3 = exp2f(s2b[r + 1] - nm);
            sumS += p2 + p3;
            *(unsigned*)&PA[w][lq][32 + koff] = (unsigned)f2bf(p2) | ((unsigned)f2bf(p3) << 16);
        }

        // V fragments (kept for both P-passes)
        bf16x8 vf[4][2];
        #pragma unroll
        for (int kb = 0; kb < 4; ++kb) {
            vf[kb][0] = *(const bf16x8*)&Vt[lq][kb * 16 + 8 * half];
            vf[kb][1] = *(const bf16x8*)&Vt[32 + lq][kb * 16 + 8 * half];
        }
        #pragma unroll
        for (int kb = 0; kb < 4; ++kb) {
            bf16x8 pf = *(const bf16x8*)&PA[w][lq][kb * 16 + 8 * half];
            aS0 = __builtin_amdgcn_mfma_f32_32x32x16_bf16(pf, vf[kb][0], aS0, 0, 0, 0);
            aS1 = __builtin_amdgcn_mfma_f32_32x32x16_bf16(pf, vf[kb][1], aS1, 0, 0, 0);
        }

        // adjacency branch (band-skip when entire tile is negligible)
        int gl_ = q0w - (c0 + 63);
        int gh_ = c0 - (q0w + 31);
        int dmin = gl_ > gh_ ? gl_ : gh_;
        if (dmin < 0) dmin = 0;
        if (qpw * (float)(dmin * dmin) < 40.0f) {
            const int ib = q - c0 - 4 * half;
            #pragma unroll
            for (int sub = 0; sub < 2; ++sub) {
                int ibs = ib - sub * 32;
                #pragma unroll
                for (int r = 0; r < 16; r += 2) {
                    int koff = (r & 3) + 8 * (r >> 2);
                    int d0i = ibs - koff, d1i = d0i - 1;
                    float f0 = (float)d0i, f1 = (float)d1i;
                    float a0 = exp2f((d0i > 0 ? A1 : A0) * f0 * f0);
                    float a1 = exp2f((d1i > 0 ? A1 : A0) * f1 * f1);
                    sumA += a0 + a1;
                    *(unsigned*)&PA[w][lq][sub * 32 + koff + 4 * half] =
                        (unsigned)f2bf(a0) | ((unsigned)f2bf(a1) << 16);
                }
            }
            #pragma unroll
            for (int kb = 0; kb < 4; ++kb) {
                bf16x8 pf = *(const bf16x8*)&PA[w][lq][kb * 16 + 8 * half];
                aA0 = __builtin_amdgcn_mfma_f32_32x32x16_bf16(pf, vf[kb][0], aA0, 0, 0, 0);
                aA1 = __builtin_amdgcn_mfma_f32_32x32x16_bf16(pf, vf[kb][1], aA1, 0, 0, 0);
            }
        }
    }

    // epilogue: mix branches, degree-normalize, store
    float St = sumS + __shfl_xor(sumS, 32);
    float At = sumA + __shfl_xor(sumA, 32);
    float den = sg * St + osg * At + 1e-9f;
    if (lane < 32) scb[w][lq] = den;
    #pragma unroll
    for (int r = 0; r < 16; ++r) {
        int row = (r & 3) + 8 * (r >> 2) + 4 * half;
        float dn = scb[w][row];
        float o0 = (sg * aS0[r] + osg * aA0[r]) / dn;
        float o1 = (sg * aS1[r] + osg * aA1[r]) / dn;
        size_t base = (size_t)(b * L_ + q0w + row) * DM_ + h * DK_;
        ATT[base + lq]      = o0;
        ATT[base + 32 + lq] = o1;
    }
}

// ---------------------------------------------------------------------------
extern "C" void kernel_launch(void* const* d_in, const int* in_sizes, int n_in,
                              void* d_out, int out_size, void* d_ws, size_t ws_size,
                              hipStream_t stream)
{
    (void)in_sizes; (void)n_in; (void)out_size; (void)ws_size;
    const float* query = (const float*)d_in[0];
    const float* key   = (const float*)d_in[1];
    const float* value = (const float*)d_in[2];
    const float* Wq = (const float*)d_in[3];  const float* bq = (const float*)d_in[4];
    const float* Wk = (const float*)d_in[5];  const float* bk = (const float*)d_in[6];
    const float* Wv = (const float*)d_in[7];  const float* bv = (const float*)d_in[8];
    const float* Wg = (const float*)d_in[9];  const float* bg = (const float*)d_in[10];
    const float* lam1 = (const float*)d_in[11];
    const float* Wo = (const float*)d_in[12]; const float* bo = (const float*)d_in[13];
    float* out = (float*)d_out;

    float* ws = (float*)d_ws;
    const size_t NROW = (size_t)B_ * L_;          // 8192
    float* Kb  = ws;
    float* Vb  = ws + NROW * DM_;
    float* Qb  = ws + 2 * NROW * DM_;
    float* QPb = ws + 3 * NROW * DM_;
    float* ATTb = Qb;   // safe alias: each block reads exactly the Q region it later writes

    dim3 gg(DM_ / 64, NROW / 64);                 // (8, 128)
    gemm_nt_bias<<<gg, 256, 0, stream>>>(query, Wq, bq, Qb, (int)NROW, DM_, DM_);
    gemm_nt_bias<<<gg, 256, 0, stream>>>(key,   Wk, bk, Kb, (int)NROW, DM_, DM_);
    gemm_nt_bias<<<gg, 256, 0, stream>>>(value, Wv, bv, Vb, (int)NROW, DM_, DM_);

    gamma_kernel<<<(B_ * H_ * L_) / 16, 256, 0, stream>>>(Qb, Wg, bg, QPb);

    dim3 ga(L_ / 128, H_, B_);                    // (4, 8, 16) = 512 blocks
    attn_kernel<<<ga, 256, 0, stream>>>(Qb, Kb, Vb, QPb, lam1, ATTb);

    gemm_nt_bias<<<gg, 256, 0, stream>>>(ATTb, Wo, bo, out, (int)NROW, DM_, DM_);
}

// Round 3
// 116.109 us; speedup vs baseline: 7.6484x; 2.8557x over previous
//
#include <hip/hip_runtime.h>
#include <hip/hip_fp16.h>
#include <math.h>

#define B_  16
#define H_  8
#define L_  512
#define DM_ 512
#define DK_ 64
#define LOG2E_ 1.44269504088896340736f

typedef _Float16 f16;
typedef __attribute__((ext_vector_type(4)))  _Float16 f16x4;
typedef __attribute__((ext_vector_type(8)))  _Float16 f16x8;
typedef __attribute__((ext_vector_type(16))) float f32x16;

__device__ __forceinline__ unsigned pkh2(float a, float b) {
    __half2 h = __halves2half2(__float2half_rn(a), __float2half_rn(b));
    return *(unsigned*)&h;
}

// ---------------------------------------------------------------------------
// MFMA fp16 GEMM:  Y[M,512] = X[M,512] @ W[512,512]^T + bias
// 128x128 tile, BK=64, 512 threads (8 waves: 2 row-blocks x 4 col-blocks).
// Reg-staged with fused fp32->fp16 conversion; LDS XOR-swizzled (T2);
// next-tile global loads issued before MFMAs (latency hidden under compute).
// XF16: X is fp16 (no conversion).  OUTF32: write fp32 (final output).
// ---------------------------------------------------------------------------
template<int XF16, int OUTF32>
__global__ __launch_bounds__(512) void gemm_f16(
    const void* __restrict__ Xv, const float* __restrict__ W,
    const float* __restrict__ bias, void* __restrict__ Yv)
{
    __shared__ f16 Al[128 * 64];
    __shared__ f16 Bl[128 * 64];

    const int tid   = threadIdx.x;
    const int w     = tid >> 6;
    const int lane  = tid & 63;
    const int lq    = lane & 31;
    const int half_ = lane >> 5;
    const int wr    = w & 1;          // 64-row block
    const int wc    = w >> 1;         // 32-col block
    const int row0  = blockIdx.y * 128;
    const int col0  = blockIdx.x * 128;
    const int trow  = tid >> 2;       // staging row/col 0..127
    const int tseg  = tid & 3;        // 16-f16 segment

    f32x16 acc[2];
    #pragma unroll
    for (int rs = 0; rs < 2; ++rs)
        #pragma unroll
        for (int i = 0; i < 16; ++i) acc[rs][i] = 0.f;

    float4 xr[4], wreg[4];
    uint4  xh[2];

    // prologue: load tile 0
    {
        const int k0 = 0;
        if (XF16) {
            const f16* X = (const f16*)Xv;
            const f16* p = X + (size_t)(row0 + trow) * 512 + k0 + tseg * 16;
            xh[0] = *(const uint4*)(p);
            xh[1] = *(const uint4*)(p + 8);
        } else {
            const float* X = (const float*)Xv;
            const float* p = X + (size_t)(row0 + trow) * 512 + k0 + tseg * 16;
            xr[0] = *(const float4*)(p);     xr[1] = *(const float4*)(p + 4);
            xr[2] = *(const float4*)(p + 8); xr[3] = *(const float4*)(p + 12);
        }
        const float* q = W + (size_t)(col0 + trow) * 512 + k0 + tseg * 16;
        wreg[0] = *(const float4*)(q);     wreg[1] = *(const float4*)(q + 4);
        wreg[2] = *(const float4*)(q + 8); wreg[3] = *(const float4*)(q + 12);
    }

    for (int t = 0; t < 8; ++t) {
        __syncthreads();
        // write staged regs -> LDS (swizzled)
        {
            const unsigned base = trow * 128 + tseg * 32;
            const unsigned swz  = (trow & 7) << 4;
            uint4 c0, c1;
            if (XF16) { c0 = xh[0]; c1 = xh[1]; }
            else {
                c0.x = pkh2(xr[0].x, xr[0].y); c0.y = pkh2(xr[0].z, xr[0].w);
                c0.z = pkh2(xr[1].x, xr[1].y); c0.w = pkh2(xr[1].z, xr[1].w);
                c1.x = pkh2(xr[2].x, xr[2].y); c1.y = pkh2(xr[2].z, xr[2].w);
                c1.z = pkh2(xr[3].x, xr[3].y); c1.w = pkh2(xr[3].z, xr[3].w);
            }
            *(uint4*)((char*)Al + ((base +  0) ^ swz)) = c0;
            *(uint4*)((char*)Al + ((base + 16) ^ swz)) = c1;
            uint4 d0, d1;
            d0.x = pkh2(wreg[0].x, wreg[0].y); d0.y = pkh2(wreg[0].z, wreg[0].w);
            d0.z = pkh2(wreg[1].x, wreg[1].y); d0.w = pkh2(wreg[1].z, wreg[1].w);
            d1.x = pkh2(wreg[2].x, wreg[2].y); d1.y = pkh2(wreg[2].z, wreg[2].w);
            d1.z = pkh2(wreg[3].x, wreg[3].y); d1.w = pkh2(wreg[3].z, wreg[3].w);
            *(uint4*)((char*)Bl + ((base +  0) ^ swz)) = d0;
            *(uint4*)((char*)Bl + ((base + 16) ^ swz)) = d1;
        }
        __syncthreads();

        // issue next tile's global loads (hide latency under MFMAs)
        if (t < 7) {
            const int k0 = (t + 1) * 64;
            if (XF16) {
                const f16* X = (const f16*)Xv;
                const f16* p = X + (size_t)(row0 + trow) * 512 + k0 + tseg * 16;
                xh[0] = *(const uint4*)(p);
                xh[1] = *(const uint4*)(p + 8);
            } else {
                const float* X = (const float*)Xv;
                const float* p = X + (size_t)(row0 + trow) * 512 + k0 + tseg * 16;
                xr[0] = *(const float4*)(p);     xr[1] = *(const float4*)(p + 4);
                xr[2] = *(const float4*)(p + 8); xr[3] = *(const float4*)(p + 12);
            }
            const float* q = W + (size_t)(col0 + trow) * 512 + k0 + tseg * 16;
            wreg[0] = *(const float4*)(q);     wreg[1] = *(const float4*)(q + 4);
            wreg[2] = *(const float4*)(q + 8); wreg[3] = *(const float4*)(q + 12);
        }

        // MFMA on current tile
        const int ra0 = wr * 64 + lq;
        const int ra1 = wr * 64 + 32 + lq;
        const int rbc = wc * 32 + lq;
        #pragma unroll
        for (int ks = 0; ks < 4; ++ks) {
            const unsigned koff = ks * 32 + half_ * 16;
            f16x8 a0 = *(const f16x8*)((char*)Al + ((ra0 * 128 + koff) ^ ((ra0 & 7) << 4)));
            f16x8 a1 = *(const f16x8*)((char*)Al + ((ra1 * 128 + koff) ^ ((ra1 & 7) << 4)));
            f16x8 bf = *(const f16x8*)((char*)Bl + ((rbc * 128 + koff) ^ ((rbc & 7) << 4)));
            acc[0] = __builtin_amdgcn_mfma_f32_32x32x16_f16(a0, bf, acc[0], 0, 0, 0);
            acc[1] = __builtin_amdgcn_mfma_f32_32x32x16_f16(a1, bf, acc[1], 0, 0, 0);
        }
    }

    const float bv = bias[col0 + wc * 32 + lq];
    #pragma unroll
    for (int rs = 0; rs < 2; ++rs) {
        #pragma unroll
        for (int r = 0; r < 16; ++r) {
            const int row = row0 + wr * 64 + rs * 32 + (r & 3) + 8 * (r >> 2) + 4 * half_;
            const float v = acc[rs][r] + bv;
            const size_t off = (size_t)row * 512 + col0 + wc * 32 + lq;
            if (OUTF32) ((float*)Yv)[off] = v;
            else        ((f16*)Yv)[off]   = (f16)v;
        }
    }
}

// ---------------------------------------------------------------------------
// gamma: g = q_row @ Wg^T + bg;  qp = (|g|+1)^-2   (Q now fp16)
// ---------------------------------------------------------------------------
__global__ __launch_bounds__(256) void gamma_kernel(
    const f16* __restrict__ Q, const float* __restrict__ Wg,
    const float* __restrict__ bg, float* __restrict__ QP)
{
    __shared__ float wg[128];
    const int tid = threadIdx.x;
    if (tid < 128) wg[tid] = Wg[tid];
    __syncthreads();

    const int grp = tid >> 4;
    const int gl  = tid & 15;
    const int idx = blockIdx.x * 16 + grp;
    const int b = idx >> 12;
    const int h = (idx >> 9) & 7;
    const int l = idx & 511;

    const f16* qrow = Q + ((size_t)(b * L_ + l) * DM_ + h * DK_);
    f16x4 q4 = *(const f16x4*)&qrow[gl * 4];

    float g0 = (float)q4[0] * wg[gl * 4 + 0] + (float)q4[1] * wg[gl * 4 + 1]
             + (float)q4[2] * wg[gl * 4 + 2] + (float)q4[3] * wg[gl * 4 + 3];
    float g1 = (float)q4[0] * wg[64 + gl * 4 + 0] + (float)q4[1] * wg[64 + gl * 4 + 1]
             + (float)q4[2] * wg[64 + gl * 4 + 2] + (float)q4[3] * wg[64 + gl * 4 + 3];
    #pragma unroll
    for (int off = 8; off; off >>= 1) {
        g0 += __shfl_xor(g0, off);
        g1 += __shfl_xor(g1, off);
    }
    if (gl == 0) {
        g0 += bg[0];
        g1 += bg[1];
        float t0 = fabsf(g0) + 1.f;
        float t1 = fabsf(g1) + 1.f;
        QP[(size_t)idx * 2 + 0] = 1.f / (t0 * t0);
        QP[(size_t)idx * 2 + 1] = 1.f / (t1 * t1);
    }
}

// ---------------------------------------------------------------------------
// MFMA flash attention (all fp16 inputs).
//   p  = exp((s - m));  a = exp(-qp_sel*d^2/2)   [via exp2]
//   out = (sg*accS + (1-sg)*accA) / (sg*sumS + (1-sg)*sumA + 1e-9)
// ---------------------------------------------------------------------------
__global__ __launch_bounds__(256) void attn_kernel(
    const f16* __restrict__ Q, const f16* __restrict__ K,
    const f16* __restrict__ V, const float* __restrict__ QP,
    const float* __restrict__ lam1, f16* __restrict__ ATT)
{
    __shared__ f16 Kh[64][72];
    __shared__ f16 Vt[64][72];        // V^T: [d][c]
    __shared__ f16 PA[4][32][72];     // per-wave P bounce: [q][k]
    __shared__ float scb[4][32];

    const int tid  = threadIdx.x;
    const int w    = tid >> 6;
    const int lane = tid & 63;
    const int lq   = lane & 31;
    const int half = lane >> 5;
    const int h    = blockIdx.y;
    const int b    = blockIdx.z;
    const int q0w  = blockIdx.x * 128 + w * 32;
    const int q    = q0w + lq;

    const float sg  = 1.f / (1.f + __expf(-lam1[0]));
    const float osg = 1.f - sg;

    // Q fragments (B-operand)
    f16x8 qh[4];
    {
        const f16* qrow = Q + ((size_t)(b * L_ + q) * DM_ + h * DK_);
        #pragma unroll
        for (int db = 0; db < 4; ++db)
            qh[db] = *(const f16x8*)&qrow[db * 16 + 8 * half];
    }

    // per-row adjacency coefficients
    float A0, A1, qpw;
    {
        const float* qpp = QP + ((size_t)((b * H_ + h) * L_) + q) * 2;
        float p0 = qpp[0], p1 = qpp[1];
        A0 = -0.72134752f * p0;     // c >= q
        A1 = -0.72134752f * p1;     // c <  q
        float mn = 0.72134752f * fminf(p0, p1);
        #pragma unroll
        for (int off = 1; off < 64; off <<= 1) mn = fminf(mn, __shfl_xor(mn, off));
        qpw = mn;
    }

    f32x16 aS0, aS1, aA0, aA1;
    #pragma unroll
    for (int i = 0; i < 16; ++i) { aS0[i] = 0.f; aS1[i] = 0.f; aA0[i] = 0.f; aA1[i] = 0.f; }
    float m2 = -3.0e38f, sumS = 0.f, sumA = 0.f;

    for (int t = 0; t < 8; ++t) {
        const int c0 = t * 64;
        __syncthreads();
        // stage K and V^T (already fp16 — pure copy / transpose)
        #pragma unroll
        for (int i = 0; i < 2; ++i) {
            int task = tid + i * 256;          // 0..511
            int c = task >> 3, f8 = task & 7;
            size_t gb = (size_t)(b * L_ + c0 + c) * DM_ + h * DK_ + f8 * 8;
            f16x8 kx = *(const f16x8*)&K[gb];
            f16x8 vx = *(const f16x8*)&V[gb];
            *(f16x8*)&Kh[c][f8 * 8] = kx;
            #pragma unroll
            for (int j = 0; j < 8; ++j) Vt[f8 * 8 + j][c] = vx[j];
        }
        __syncthreads();

        // S^T = K . Q^T  (natural units)
        f32x16 s2a, s2b;
        #pragma unroll
        for (int i = 0; i < 16; ++i) { s2a[i] = 0.f; s2b[i] = 0.f; }
        #pragma unroll
        for (int db = 0; db < 4; ++db) {
            const int dof = db * 16 + 8 * half;
            f16x8 ka  = *(const f16x8*)&Kh[lq][dof];
            f16x8 kb2 = *(const f16x8*)&Kh[32 + lq][dof];
            s2a = __builtin_amdgcn_mfma_f32_32x32x16_f16(ka,  qh[db], s2a, 0, 0, 0);
            s2b = __builtin_amdgcn_mfma_f32_32x32x16_f16(kb2, qh[db], s2b, 0, 0, 0);
        }

        // online max
        float tm = s2a[0];
        #pragma unroll
        for (int i = 1; i < 16; ++i) tm = fmaxf(tm, s2a[i]);
        #pragma unroll
        for (int i = 0; i < 16; ++i) tm = fmaxf(tm, s2b[i]);
        tm = fmaxf(tm, __shfl_xor(tm, 32));
        float nm = fmaxf(m2, tm);
        float sc = exp2f((m2 - nm) * LOG2E_);
        m2 = nm;
        sumS *= sc;
        if (lane < 32) scb[w][lq] = sc;
        #pragma unroll
        for (int r = 0; r < 16; ++r) {
            float s_ = scb[w][(r & 3) + 8 * (r >> 2) + 4 * half];
            aS0[r] *= s_;
            aS1[r] *= s_;
        }

        // p = exp(s - nm); pack fp16 into PA
        const float nmL = nm * LOG2E_;
        #pragma unroll
        for (int r = 0; r < 16; r += 2) {
            int koff = (r & 3) + 8 * (r >> 2) + 4 * half;
            float p0 = exp2f(fmaf(s2a[r], LOG2E_, -nmL));
            float p1 = exp2f(fmaf(s2a[r + 1], LOG2E_, -nmL));
            sumS += p0 + p1;
            *(unsigned*)&PA[w][lq][koff] = pkh2(p0, p1);
            float p2 = exp2f(fmaf(s2b[r], LOG2E_, -nmL));
            float p3 = exp2f(fmaf(s2b[r + 1], LOG2E_, -nmL));
            sumS += p2 + p3;
            *(unsigned*)&PA[w][lq][32 + koff] = pkh2(p2, p3);
        }

        // V fragments (reused by both P-passes)
        f16x8 vf[4][2];
        #pragma unroll
        for (int kb = 0; kb < 4; ++kb) {
            vf[kb][0] = *(const f16x8*)&Vt[lq][kb * 16 + 8 * half];
            vf[kb][1] = *(const f16x8*)&Vt[32 + lq][kb * 16 + 8 * half];
        }
        #pragma unroll
        for (int kb = 0; kb < 4; ++kb) {
            f16x8 pf = *(const f16x8*)&PA[w][lq][kb * 16 + 8 * half];
            aS0 = __builtin_amdgcn_mfma_f32_32x32x16_f16(pf, vf[kb][0], aS0, 0, 0, 0);
            aS1 = __builtin_amdgcn_mfma_f32_32x32x16_f16(pf, vf[kb][1], aS1, 0, 0, 0);
        }

        // adjacency branch (band-skip far tiles)
        int gl_ = q0w - (c0 + 63);
        int gh_ = c0 - (q0w + 31);
        int dmin = gl_ > gh_ ? gl_ : gh_;
        if (dmin < 0) dmin = 0;
        if (qpw * (float)(dmin * dmin) < 40.0f) {
            const int ib = q - c0 - 4 * half;
            #pragma unroll
            for (int sub = 0; sub < 2; ++sub) {
                int ibs = ib - sub * 32;
                #pragma unroll
                for (int r = 0; r < 16; r += 2) {
                    int koff = (r & 3) + 8 * (r >> 2);
                    int d0i = ibs - koff, d1i = d0i - 1;
                    float f0 = (float)d0i, f1 = (float)d1i;
                    float a0 = exp2f((d0i > 0 ? A1 : A0) * f0 * f0);
                    float a1 = exp2f((d1i > 0 ? A1 : A0) * f1 * f1);
                    sumA += a0 + a1;
                    *(unsigned*)&PA[w][lq][sub * 32 + koff + 4 * half] = pkh2(a0, a1);
                }
            }
            #pragma unroll
            for (int kb = 0; kb < 4; ++kb) {
                f16x8 pf = *(const f16x8*)&PA[w][lq][kb * 16 + 8 * half];
                aA0 = __builtin_amdgcn_mfma_f32_32x32x16_f16(pf, vf[kb][0], aA0, 0, 0, 0);
                aA1 = __builtin_amdgcn_mfma_f32_32x32x16_f16(pf, vf[kb][1], aA1, 0, 0, 0);
            }
        }
    }

    // epilogue
    float St = sumS + __shfl_xor(sumS, 32);
    float At = sumA + __shfl_xor(sumA, 32);
    float den = sg * St + osg * At + 1e-9f;
    if (lane < 32) scb[w][lq] = den;
    #pragma unroll
    for (int r = 0; r < 16; ++r) {
        int row = (r & 3) + 8 * (r >> 2) + 4 * half;
        float dn = scb[w][row];
        float o0 = (sg * aS0[r] + osg * aA0[r]) / dn;
        float o1 = (sg * aS1[r] + osg * aA1[r]) / dn;
        size_t base = (size_t)(b * L_ + q0w + row) * DM_ + h * DK_;
        ATT[base + lq]      = (f16)o0;
        ATT[base + 32 + lq] = (f16)o1;
    }
}

// ---------------------------------------------------------------------------
extern "C" void kernel_launch(void* const* d_in, const int* in_sizes, int n_in,
                              void* d_out, int out_size, void* d_ws, size_t ws_size,
                              hipStream_t stream)
{
    (void)in_sizes; (void)n_in; (void)out_size; (void)ws_size;
    const float* query = (const float*)d_in[0];
    const float* key   = (const float*)d_in[1];
    const float* value = (const float*)d_in[2];
    const float* Wq = (const float*)d_in[3];  const float* bq = (const float*)d_in[4];
    const float* Wk = (const float*)d_in[5];  const float* bk = (const float*)d_in[6];
    const float* Wv = (const float*)d_in[7];  const float* bv = (const float*)d_in[8];
    const float* Wg = (const float*)d_in[9];  const float* bg = (const float*)d_in[10];
    const float* lam1 = (const float*)d_in[11];
    const float* Wo = (const float*)d_in[12]; const float* bo = (const float*)d_in[13];

    f16* ws16 = (f16*)d_ws;
    const size_t NR = (size_t)B_ * L_ * DM_;      // 4 Mi elements
    f16* Kb  = ws16;
    f16* Vb  = ws16 + NR;
    f16* Qb  = ws16 + 2 * NR;
    float* QPb = (float*)(ws16 + 3 * NR);
    f16* ATTb = Qb;   // safe alias: each block reads exactly the Q region it later writes

    dim3 gg(4, 64);   // (N/128, M/128)
    gemm_f16<0, 0><<<gg, 512, 0, stream>>>(query, Wq, bq, Qb);
    gemm_f16<0, 0><<<gg, 512, 0, stream>>>(key,   Wk, bk, Kb);
    gemm_f16<0, 0><<<gg, 512, 0, stream>>>(value, Wv, bv, Vb);

    gamma_kernel<<<(B_ * H_ * L_) / 16, 256, 0, stream>>>(Qb, Wg, bg, QPb);

    dim3 ga(L_ / 128, H_, B_);                    // (4, 8, 16)
    attn_kernel<<<ga, 256, 0, stream>>>(Qb, Kb, Vb, QPb, lam1, ATTb);

    gemm_f16<1, 1><<<gg, 512, 0, stream>>>(Qb, Wo, bo, (float*)d_out);
}

// Round 5
// 114.552 us; speedup vs baseline: 7.7524x; 1.0136x over previous
//
#include <hip/hip_runtime.h>
#include <hip/hip_fp16.h>
#include <math.h>

#define B_  16
#define H_  8
#define L_  512
#define DM_ 512
#define DK_ 64
#define LOG2E_ 1.44269504088896340736f
#define NLOG2E_H_ 0.72134752044f   // 0.5 * log2(e)

typedef _Float16 f16;
typedef __attribute__((ext_vector_type(2)))  __fp16   fp16v2;
typedef __attribute__((ext_vector_type(8)))  _Float16 f16x8;
typedef __attribute__((ext_vector_type(16))) float f32x16;

__device__ __forceinline__ unsigned pkrtz(float a, float b) {
    union { fp16v2 v; unsigned u; } cv;
    cv.v = __builtin_amdgcn_cvt_pkrtz(a, b);
    return cv.u;
}
// v_permlane32_swap_b32: x[lanes 32..63] <-> y[lanes 0..31]
__device__ __forceinline__ void plswap(unsigned &x, unsigned &y) {
    asm volatile("v_permlane32_swap_b32 %0, %1" : "+v"(x), "+v"(y));
}

// ---------------------------------------------------------------------------
// MFMA fp16 GEMM core:  Y = X[M,512] @ W[512,512]^T + bias
// 128x128 tile, BK=64, 512 threads (8 waves).  Reg-staged fp32->fp16,
// LDS XOR-swizzled, next-tile loads issued before MFMAs.
// TRANSOUT: swap operands -> compute Y^T, store [(b*512+n)][l] (for V^T).
// ---------------------------------------------------------------------------
template<int XF16, int OUTF32, int TRANSOUT>
__device__ __forceinline__ void gemm_core(
    const void* __restrict__ Xv, const float* __restrict__ W,
    const float* __restrict__ bias, void* __restrict__ Yv)
{
    __shared__ f16 Al[128 * 64];
    __shared__ f16 Bl[128 * 64];

    const int tid   = threadIdx.x;
    const int w     = tid >> 6;
    const int lane  = tid & 63;
    const int lq    = lane & 31;
    const int half_ = lane >> 5;
    const int wr    = w & 1;
    const int wc    = w >> 1;
    const int row0  = blockIdx.y * 128;
    const int col0  = blockIdx.x * 128;
    const int trow  = tid >> 2;
    const int tseg  = tid & 3;

    f32x16 acc[2];
    #pragma unroll
    for (int rs = 0; rs < 2; ++rs)
        #pragma unroll
        for (int i = 0; i < 16; ++i) acc[rs][i] = 0.f;

    float4 xr[4], wreg[4];
    uint4  xh[2];

    {
        if (XF16) {
            const f16* X = (const f16*)Xv;
            const f16* p = X + (size_t)(row0 + trow) * 512 + tseg * 16;
            xh[0] = *(const uint4*)(p);
            xh[1] = *(const uint4*)(p + 8);
        } else {
            const float* X = (const float*)Xv;
            const float* p = X + (size_t)(row0 + trow) * 512 + tseg * 16;
            xr[0] = *(const float4*)(p);     xr[1] = *(const float4*)(p + 4);
            xr[2] = *(const float4*)(p + 8); xr[3] = *(const float4*)(p + 12);
        }
        const float* q = W + (size_t)(col0 + trow) * 512 + tseg * 16;
        wreg[0] = *(const float4*)(q);     wreg[1] = *(const float4*)(q + 4);
        wreg[2] = *(const float4*)(q + 8); wreg[3] = *(const float4*)(q + 12);
    }

    for (int t = 0; t < 8; ++t) {
        __syncthreads();
        {
            const unsigned base = trow * 128 + tseg * 32;
            const unsigned swz  = (trow & 7) << 4;
            uint4 c0, c1;
            if (XF16) { c0 = xh[0]; c1 = xh[1]; }
            else {
                c0.x = pkrtz(xr[0].x, xr[0].y); c0.y = pkrtz(xr[0].z, xr[0].w);
                c0.z = pkrtz(xr[1].x, xr[1].y); c0.w = pkrtz(xr[1].z, xr[1].w);
                c1.x = pkrtz(xr[2].x, xr[2].y); c1.y = pkrtz(xr[2].z, xr[2].w);
                c1.z = pkrtz(xr[3].x, xr[3].y); c1.w = pkrtz(xr[3].z, xr[3].w);
            }
            *(uint4*)((char*)Al + ((base +  0) ^ swz)) = c0;
            *(uint4*)((char*)Al + ((base + 16) ^ swz)) = c1;
            uint4 d0, d1;
            d0.x = pkrtz(wreg[0].x, wreg[0].y); d0.y = pkrtz(wreg[0].z, wreg[0].w);
            d0.z = pkrtz(wreg[1].x, wreg[1].y); d0.w = pkrtz(wreg[1].z, wreg[1].w);
            d1.x = pkrtz(wreg[2].x, wreg[2].y); d1.y = pkrtz(wreg[2].z, wreg[2].w);
            d1.z = pkrtz(wreg[3].x, wreg[3].y); d1.w = pkrtz(wreg[3].z, wreg[3].w);
            *(uint4*)((char*)Bl + ((base +  0) ^ swz)) = d0;
            *(uint4*)((char*)Bl + ((base + 16) ^ swz)) = d1;
        }
        __syncthreads();

        if (t < 7) {
            const int k0 = (t + 1) * 64;
            if (XF16) {
                const f16* X = (const f16*)Xv;
                const f16* p = X + (size_t)(row0 + trow) * 512 + k0 + tseg * 16;
                xh[0] = *(const uint4*)(p);
                xh[1] = *(const uint4*)(p + 8);
            } else {
                const float* X = (const float*)Xv;
                const float* p = X + (size_t)(row0 + trow) * 512 + k0 + tseg * 16;
                xr[0] = *(const float4*)(p);     xr[1] = *(const float4*)(p + 4);
                xr[2] = *(const float4*)(p + 8); xr[3] = *(const float4*)(p + 12);
            }
            const float* q = W + (size_t)(col0 + trow) * 512 + k0 + tseg * 16;
            wreg[0] = *(const float4*)(q);     wreg[1] = *(const float4*)(q + 4);
            wreg[2] = *(const float4*)(q + 8); wreg[3] = *(const float4*)(q + 12);
        }

        const int ra0 = wr * 64 + lq;
        const int ra1 = wr * 64 + 32 + lq;
        const int rbc = wc * 32 + lq;
        #pragma unroll
        for (int ks = 0; ks < 4; ++ks) {
            const unsigned koff = ks * 32 + half_ * 16;
            f16x8 a0, a1, bf;
            if (TRANSOUT) {
                a0 = *(const f16x8*)((char*)Bl + ((ra0 * 128 + koff) ^ ((ra0 & 7) << 4)));
                a1 = *(const f16x8*)((char*)Bl + ((ra1 * 128 + koff) ^ ((ra1 & 7) << 4)));
                bf = *(const f16x8*)((char*)Al + ((rbc * 128 + koff) ^ ((rbc & 7) << 4)));
            } else {
                a0 = *(const f16x8*)((char*)Al + ((ra0 * 128 + koff) ^ ((ra0 & 7) << 4)));
                a1 = *(const f16x8*)((char*)Al + ((ra1 * 128 + koff) ^ ((ra1 & 7) << 4)));
                bf = *(const f16x8*)((char*)Bl + ((rbc * 128 + koff) ^ ((rbc & 7) << 4)));
            }
            acc[0] = __builtin_amdgcn_mfma_f32_32x32x16_f16(a0, bf, acc[0], 0, 0, 0);
            acc[1] = __builtin_amdgcn_mfma_f32_32x32x16_f16(a1, bf, acc[1], 0, 0, 0);
        }
    }

    if (TRANSOUT) {
        // acc[rs][r] = Y^T[n = col0+wr*64+rs*32+crow][l = row0+wc*32+lq]
        const int lg = row0 + wc * 32 + lq;
        const int bI = lg >> 9, ll = lg & 511;
        #pragma unroll
        for (int rs = 0; rs < 2; ++rs) {
            #pragma unroll
            for (int r = 0; r < 16; ++r) {
                const int n = col0 + wr * 64 + rs * 32 + (r & 3) + 8 * (r >> 2) + 4 * half_;
                const float v = acc[rs][r] + bias[n];
                ((f16*)Yv)[((size_t)(bI * 512 + n)) * 512 + ll] = (f16)v;
            }
        }
    } else {
        const float bv = bias[col0 + wc * 32 + lq];
        #pragma unroll
        for (int rs = 0; rs < 2; ++rs) {
            #pragma unroll
            for (int r = 0; r < 16; ++r) {
                const int row = row0 + wr * 64 + rs * 32 + (r & 3) + 8 * (r >> 2) + 4 * half_;
                const float v = acc[rs][r] + bv;
                const size_t off = (size_t)row * 512 + col0 + wc * 32 + lq;
                if (OUTF32) ((float*)Yv)[off] = v;
                else        ((f16*)Yv)[off]   = (f16)v;
            }
        }
    }
}

__global__ __launch_bounds__(512) void gemm_qk(
    const float* __restrict__ q, const float* __restrict__ k,
    const float* __restrict__ Wq, const float* __restrict__ bq,
    const float* __restrict__ Wk, const float* __restrict__ bk,
    void* __restrict__ Qb, void* __restrict__ Kb)
{
    const float* X = blockIdx.z ? k : q;
    const float* W = blockIdx.z ? Wk : Wq;
    const float* bb = blockIdx.z ? bk : bq;
    void* Y = blockIdx.z ? Kb : Qb;
    gemm_core<0, 0, 0>(X, W, bb, Y);
}

__global__ __launch_bounds__(512) void gemm_v(
    const float* __restrict__ v, const float* __restrict__ Wv,
    const float* __restrict__ bv, void* __restrict__ VT)
{
    gemm_core<0, 0, 1>(v, Wv, bv, VT);
}

__global__ __launch_bounds__(512) void gemm_o(
    const void* __restrict__ X, const float* __restrict__ Wo,
    const float* __restrict__ bo, void* __restrict__ Y)
{
    gemm_core<1, 1, 0>(X, Wo, bo, Y);
}

// ---------------------------------------------------------------------------
// MFMA flash attention, fused gamma, in-register P/A fragments.
//   S^T = mfma(K,Q): lane owns q-col, regs own k.  P packed via cvt_pkrtz and
//   redistributed with v_permlane32_swap into PV A-fragments (no LDS bounce).
//   V arrives pre-transposed (VT[(b*512+h*64+d)][l]) -> staging is a pure copy.
// ---------------------------------------------------------------------------
__global__ __launch_bounds__(256) void attn_kernel(
    const f16* __restrict__ Q, const f16* __restrict__ K,
    const f16* __restrict__ VT, const float* __restrict__ Wg,
    const float* __restrict__ bg, const float* __restrict__ lam1,
    f16* __restrict__ ATT)
{
    __shared__ f16 Kh[64][72];
    __shared__ f16 Vt[64][72];        // V^T tile: [d][c]
    __shared__ float wgl[128];
    __shared__ float scb[4][32];

    const int tid  = threadIdx.x;
    const int w    = tid >> 6;
    const int lane = tid & 63;
    const int lq   = lane & 31;
    const int half = lane >> 5;
    const int h    = blockIdx.y;
    const int b    = blockIdx.z;
    const int q0w  = blockIdx.x * 128 + w * 32;
    const int q    = q0w + lq;

    const float sg  = 1.f / (1.f + __expf(-lam1[0]));
    const float osg = 1.f - sg;

    if (tid < 128) wgl[tid] = Wg[tid];

    // Q fragments (B-operand), raw fp16
    f16x8 qh[4];
    {
        const f16* qrow = Q + ((size_t)(b * L_ + q) * DM_ + h * DK_);
        #pragma unroll
        for (int db = 0; db < 4; ++db)
            qh[db] = *(const f16x8*)&qrow[db * 16 + 8 * half];
    }
    __syncthreads();

    // fused gamma: g = q_row . Wg^T + bg ; qp = (|g|+1)^-2
    float A0, A1, qpw;
    {
        float g0 = 0.f, g1 = 0.f;
        #pragma unroll
        for (int db = 0; db < 4; ++db)
            #pragma unroll
            for (int j = 0; j < 8; ++j) {
                const int d = db * 16 + 8 * half + j;
                const float qv = (float)qh[db][j];
                g0 = fmaf(qv, wgl[d], g0);
                g1 = fmaf(qv, wgl[64 + d], g1);
            }
        g0 += __shfl_xor(g0, 32);
        g1 += __shfl_xor(g1, 32);
        g0 += bg[0];
        g1 += bg[1];
        const float t0 = fabsf(g0) + 1.f, t1 = fabsf(g1) + 1.f;
        const float p0 = 1.f / (t0 * t0), p1 = 1.f / (t1 * t1);
        A0 = -NLOG2E_H_ * p0;       // c >= q (triu)
        A1 = -NLOG2E_H_ * p1;       // c <  q (tril)
        float mn = NLOG2E_H_ * fminf(p0, p1);
        #pragma unroll
        for (int off = 1; off < 64; off <<= 1) mn = fminf(mn, __shfl_xor(mn, off));
        qpw = mn;
    }

    f32x16 aS0, aS1, aA0, aA1;
    #pragma unroll
    for (int i = 0; i < 16; ++i) { aS0[i] = 0.f; aS1[i] = 0.f; aA0[i] = 0.f; aA1[i] = 0.f; }
    float m2 = -3.0e38f, sumS = 0.f, sumA = 0.f;

    for (int t = 0; t < 8; ++t) {
        const int c0 = t * 64;
        __syncthreads();
        // stage K and V^T tiles — both pure vectorized copies
        #pragma unroll
        for (int i = 0; i < 2; ++i) {
            const int task = tid + i * 256;       // 0..511
            const int r = task >> 3, seg = task & 7;
            *(uint4*)&Kh[r][seg * 8] =
                *(const uint4*)&K[(size_t)(b * L_ + c0 + r) * DM_ + h * DK_ + seg * 8];
            *(uint4*)&Vt[r][seg * 8] =
                *(const uint4*)&VT[(size_t)(b * L_ + h * DK_ + r) * L_ + c0 + seg * 8];
        }
        __syncthreads();

        // S^T = K . Q^T
        f32x16 s2a, s2b;
        #pragma unroll
        for (int i = 0; i < 16; ++i) { s2a[i] = 0.f; s2b[i] = 0.f; }
        #pragma unroll
        for (int db = 0; db < 4; ++db) {
            const int dof = db * 16 + 8 * half;
            f16x8 ka  = *(const f16x8*)&Kh[lq][dof];
            f16x8 kb2 = *(const f16x8*)&Kh[32 + lq][dof];
            s2a = __builtin_amdgcn_mfma_f32_32x32x16_f16(ka,  qh[db], s2a, 0, 0, 0);
            s2b = __builtin_amdgcn_mfma_f32_32x32x16_f16(kb2, qh[db], s2b, 0, 0, 0);
        }

        // online max (lane owns q; halves hold complementary k's)
        float tm = s2a[0];
        #pragma unroll
        for (int i = 1; i < 16; ++i) tm = fmaxf(tm, s2a[i]);
        #pragma unroll
        for (int i = 0; i < 16; ++i) tm = fmaxf(tm, s2b[i]);
        tm = fmaxf(tm, __shfl_xor(tm, 32));
        const float nm = fmaxf(m2, tm);
        const float sc = exp2f((m2 - nm) * LOG2E_);
        m2 = nm;
        sumS *= sc;
        if (lane < 32) scb[w][lq] = sc;
        #pragma unroll
        for (int r = 0; r < 16; ++r) {
            const float s_ = scb[w][(r & 3) + 8 * (r >> 2) + 4 * half];
            aS0[r] *= s_;
            aS1[r] *= s_;
        }

        // V fragments
        f16x8 vfa[4], vfb[4];
        #pragma unroll
        for (int ks = 0; ks < 4; ++ks) {
            vfa[ks] = *(const f16x8*)&Vt[lq][ks * 16 + 8 * half];
            vfb[ks] = *(const f16x8*)&Vt[32 + lq][ks * 16 + 8 * half];
        }

        // P: exp, pack, permlane-swap into A-fragments, PV MFMAs
        const float nmL = nm * LOG2E_;
        #pragma unroll
        for (int sub = 0; sub < 2; ++sub) {
            const f32x16& s2 = sub ? s2b : s2a;
            #pragma unroll
            for (int ksl = 0; ksl < 2; ++ksl) {
                const int rb = ksl * 8;
                float p[8];
                #pragma unroll
                for (int rr = 0; rr < 8; ++rr) {
                    p[rr] = exp2f(fmaf(s2[rb + rr], LOG2E_, -nmL));
                    sumS += p[rr];
                }
                union { unsigned u[4]; f16x8 v; } f;
                f.u[0] = pkrtz(p[0], p[1]);
                f.u[1] = pkrtz(p[2], p[3]);
                f.u[2] = pkrtz(p[4], p[5]);
                f.u[3] = pkrtz(p[6], p[7]);
                plswap(f.u[0], f.u[2]);
                plswap(f.u[1], f.u[3]);
                const int ks = sub * 2 + ksl;
                aS0 = __builtin_amdgcn_mfma_f32_32x32x16_f16(f.v, vfa[ks], aS0, 0, 0, 0);
                aS1 = __builtin_amdgcn_mfma_f32_32x32x16_f16(f.v, vfb[ks], aS1, 0, 0, 0);
            }
        }

        // adjacency branch (band-skip far tiles; diagonal tile never skipped)
        int gl_ = q0w - (c0 + 63);
        int gh_ = c0 - (q0w + 31);
        int dmin = gl_ > gh_ ? gl_ : gh_;
        if (dmin < 0) dmin = 0;
        if (qpw * (float)(dmin * dmin) < 40.0f) {
            #pragma unroll
            for (int sub = 0; sub < 2; ++sub) {
                #pragma unroll
                for (int ksl = 0; ksl < 2; ++ksl) {
                    float a[8];
                    #pragma unroll
                    for (int rr = 0; rr < 8; ++rr) {
                        const int kk = (rr & 3) + 8 * (rr >> 2) + 16 * ksl + 4 * half;
                        const int diff = q - (c0 + sub * 32 + kk);
                        const float fd = (float)diff;
                        const float coef = diff > 0 ? A1 : A0;
                        a[rr] = exp2f(coef * fd * fd);
                        sumA += a[rr];
                    }
                    union { unsigned u[4]; f16x8 v; } f;
                    f.u[0] = pkrtz(a[0], a[1]);
                    f.u[1] = pkrtz(a[2], a[3]);
                    f.u[2] = pkrtz(a[4], a[5]);
                    f.u[3] = pkrtz(a[6], a[7]);
                    plswap(f.u[0], f.u[2]);
                    plswap(f.u[1], f.u[3]);
                    const int ks = sub * 2 + ksl;
                    aA0 = __builtin_amdgcn_mfma_f32_32x32x16_f16(f.v, vfa[ks], aA0, 0, 0, 0);
                    aA1 = __builtin_amdgcn_mfma_f32_32x32x16_f16(f.v, vfb[ks], aA1, 0, 0, 0);
                }
            }
        }
    }

    // epilogue: mix branches, degree-normalize, store
    const float St = sumS + __shfl_xor(sumS, 32);
    const float At = sumA + __shfl_xor(sumA, 32);
    const float den = sg * St + osg * At + 1e-9f;
    if (lane < 32) scb[w][lq] = den;
    #pragma unroll
    for (int r = 0; r < 16; ++r) {
        const int row = (r & 3) + 8 * (r >> 2) + 4 * half;
        const float dn = scb[w][row];
        const float o0 = (sg * aS0[r] + osg * aA0[r]) / dn;
        const float o1 = (sg * aS1[r] + osg * aA1[r]) / dn;
        const size_t base = (size_t)(b * L_ + q0w + row) * DM_ + h * DK_;
        ATT[base + lq]      = (f16)o0;
        ATT[base + 32 + lq] = (f16)o1;
    }
}

// ---------------------------------------------------------------------------
extern "C" void kernel_launch(void* const* d_in, const int* in_sizes, int n_in,
                              void* d_out, int out_size, void* d_ws, size_t ws_size,
                              hipStream_t stream)
{
    (void)in_sizes; (void)n_in; (void)out_size; (void)ws_size;
    const float* query = (const float*)d_in[0];
    const float* key   = (const float*)d_in[1];
    const float* value = (const float*)d_in[2];
    const float* Wq = (const float*)d_in[3];  const float* bq = (const float*)d_in[4];
    const float* Wk = (const float*)d_in[5];  const float* bk = (const float*)d_in[6];
    const float* Wv = (const float*)d_in[7];  const float* bv = (const float*)d_in[8];
    const float* Wg = (const float*)d_in[9];  const float* bg = (const float*)d_in[10];
    const float* lam1 = (const float*)d_in[11];
    const float* Wo = (const float*)d_in[12]; const float* bo = (const float*)d_in[13];

    f16* ws16 = (f16*)d_ws;
    const size_t NR = (size_t)B_ * L_ * DM_;
    f16* Kb  = ws16;
    f16* VTb = ws16 + NR;
    f16* Qb  = ws16 + 2 * NR;
    f16* ATTb = Qb;   // safe alias: each wave reads exactly the Q cells it later writes

    dim3 gqk(4, 64, 2);
    gemm_qk<<<gqk, 512, 0, stream>>>(query, key, Wq, bq, Wk, bk, Qb, Kb);
    dim3 gg(4, 64);
    gemm_v<<<gg, 512, 0, stream>>>(value, Wv, bv, VTb);

    dim3 ga(L_ / 128, H_, B_);
    attn_kernel<<<ga, 256, 0, stream>>>(Qb, Kb, VTb, Wg, bg, lam1, ATTb);

    gemm_o<<<gg, 512, 0, stream>>>(Qb, Wo, bo, (float*)d_out);
}

// Round 6
// 108.006 us; speedup vs baseline: 8.2222x; 1.0606x over previous
//
#include <hip/hip_runtime.h>
#include <hip/hip_fp16.h>
#include <math.h>

#define B_  16
#define H_  8
#define L_  512
#define DM_ 512
#define DK_ 64
#define LOG2E_ 1.44269504088896340736f
#define NLOG2E_H_ 0.72134752044f   // 0.5 * log2(e)

typedef _Float16 f16;
typedef __attribute__((ext_vector_type(2)))  __fp16   fp16v2;
typedef __attribute__((ext_vector_type(8)))  _Float16 f16x8;
typedef __attribute__((ext_vector_type(16))) float f32x16;

__device__ __forceinline__ unsigned pkrtz(float a, float b) {
    union { fp16v2 v; unsigned u; } cv;
    cv.v = __builtin_amdgcn_cvt_pkrtz(a, b);
    return cv.u;
}
// v_permlane32_swap_b32: x[lanes 32..63] <-> y[lanes 0..31]
// NOT volatile: pure register op, let the scheduler move it.
__device__ __forceinline__ void plswap(unsigned &x, unsigned &y) {
    asm("v_permlane32_swap_b32 %0, %1" : "+v"(x), "+v"(y));
}

// ---------------------------------------------------------------------------
// MFMA fp16 GEMM core:  Y = X[M,512] @ W[512,512]^T + bias   (unchanged)
// ---------------------------------------------------------------------------
template<int XF16, int OUTF32, int TRANSOUT>
__device__ __forceinline__ void gemm_core(
    const void* __restrict__ Xv, const float* __restrict__ W,
    const float* __restrict__ bias, void* __restrict__ Yv)
{
    __shared__ f16 Al[128 * 64];
    __shared__ f16 Bl[128 * 64];

    const int tid   = threadIdx.x;
    const int w     = tid >> 6;
    const int lane  = tid & 63;
    const int lq    = lane & 31;
    const int half_ = lane >> 5;
    const int wr    = w & 1;
    const int wc    = w >> 1;
    const int row0  = blockIdx.y * 128;
    const int col0  = blockIdx.x * 128;
    const int trow  = tid >> 2;
    const int tseg  = tid & 3;

    f32x16 acc[2];
    #pragma unroll
    for (int rs = 0; rs < 2; ++rs)
        #pragma unroll
        for (int i = 0; i < 16; ++i) acc[rs][i] = 0.f;

    float4 xr[4], wreg[4];
    uint4  xh[2];

    {
        if (XF16) {
            const f16* X = (const f16*)Xv;
            const f16* p = X + (size_t)(row0 + trow) * 512 + tseg * 16;
            xh[0] = *(const uint4*)(p);
            xh[1] = *(const uint4*)(p + 8);
        } else {
            const float* X = (const float*)Xv;
            const float* p = X + (size_t)(row0 + trow) * 512 + tseg * 16;
            xr[0] = *(const float4*)(p);     xr[1] = *(const float4*)(p + 4);
            xr[2] = *(const float4*)(p + 8); xr[3] = *(const float4*)(p + 12);
        }
        const float* q = W + (size_t)(col0 + trow) * 512 + tseg * 16;
        wreg[0] = *(const float4*)(q);     wreg[1] = *(const float4*)(q + 4);
        wreg[2] = *(const float4*)(q + 8); wreg[3] = *(const float4*)(q + 12);
    }

    for (int t = 0; t < 8; ++t) {
        __syncthreads();
        {
            const unsigned base = trow * 128 + tseg * 32;
            const unsigned swz  = (trow & 7) << 4;
            uint4 c0, c1;
            if (XF16) { c0 = xh[0]; c1 = xh[1]; }
            else {
                c0.x = pkrtz(xr[0].x, xr[0].y); c0.y = pkrtz(xr[0].z, xr[0].w);
                c0.z = pkrtz(xr[1].x, xr[1].y); c0.w = pkrtz(xr[1].z, xr[1].w);
                c1.x = pkrtz(xr[2].x, xr[2].y); c1.y = pkrtz(xr[2].z, xr[2].w);
                c1.z = pkrtz(xr[3].x, xr[3].y); c1.w = pkrtz(xr[3].z, xr[3].w);
            }
            *(uint4*)((char*)Al + ((base +  0) ^ swz)) = c0;
            *(uint4*)((char*)Al + ((base + 16) ^ swz)) = c1;
            uint4 d0, d1;
            d0.x = pkrtz(wreg[0].x, wreg[0].y); d0.y = pkrtz(wreg[0].z, wreg[0].w);
            d0.z = pkrtz(wreg[1].x, wreg[1].y); d0.w = pkrtz(wreg[1].z, wreg[1].w);
            d1.x = pkrtz(wreg[2].x, wreg[2].y); d1.y = pkrtz(wreg[2].z, wreg[2].w);
            d1.z = pkrtz(wreg[3].x, wreg[3].y); d1.w = pkrtz(wreg[3].z, wreg[3].w);
            *(uint4*)((char*)Bl + ((base +  0) ^ swz)) = d0;
            *(uint4*)((char*)Bl + ((base + 16) ^ swz)) = d1;
        }
        __syncthreads();

        if (t < 7) {
            const int k0 = (t + 1) * 64;
            if (XF16) {
                const f16* X = (const f16*)Xv;
                const f16* p = X + (size_t)(row0 + trow) * 512 + k0 + tseg * 16;
                xh[0] = *(const uint4*)(p);
                xh[1] = *(const uint4*)(p + 8);
            } else {
                const float* X = (const float*)Xv;
                const float* p = X + (size_t)(row0 + trow) * 512 + k0 + tseg * 16;
                xr[0] = *(const float4*)(p);     xr[1] = *(const float4*)(p + 4);
                xr[2] = *(const float4*)(p + 8); xr[3] = *(const float4*)(p + 12);
            }
            const float* q = W + (size_t)(col0 + trow) * 512 + k0 + tseg * 16;
            wreg[0] = *(const float4*)(q);     wreg[1] = *(const float4*)(q + 4);
            wreg[2] = *(const float4*)(q + 8); wreg[3] = *(const float4*)(q + 12);
        }

        const int ra0 = wr * 64 + lq;
        const int ra1 = wr * 64 + 32 + lq;
        const int rbc = wc * 32 + lq;
        #pragma unroll
        for (int ks = 0; ks < 4; ++ks) {
            const unsigned koff = ks * 32 + half_ * 16;
            f16x8 a0, a1, bf;
            if (TRANSOUT) {
                a0 = *(const f16x8*)((char*)Bl + ((ra0 * 128 + koff) ^ ((ra0 & 7) << 4)));
                a1 = *(const f16x8*)((char*)Bl + ((ra1 * 128 + koff) ^ ((ra1 & 7) << 4)));
                bf = *(const f16x8*)((char*)Al + ((rbc * 128 + koff) ^ ((rbc & 7) << 4)));
            } else {
                a0 = *(const f16x8*)((char*)Al + ((ra0 * 128 + koff) ^ ((ra0 & 7) << 4)));
                a1 = *(const f16x8*)((char*)Al + ((ra1 * 128 + koff) ^ ((ra1 & 7) << 4)));
                bf = *(const f16x8*)((char*)Bl + ((rbc * 128 + koff) ^ ((rbc & 7) << 4)));
            }
            acc[0] = __builtin_amdgcn_mfma_f32_32x32x16_f16(a0, bf, acc[0], 0, 0, 0);
            acc[1] = __builtin_amdgcn_mfma_f32_32x32x16_f16(a1, bf, acc[1], 0, 0, 0);
        }
    }

    if (TRANSOUT) {
        const int lg = row0 + wc * 32 + lq;
        const int bI = lg >> 9, ll = lg & 511;
        #pragma unroll
        for (int rs = 0; rs < 2; ++rs) {
            #pragma unroll
            for (int r = 0; r < 16; ++r) {
                const int n = col0 + wr * 64 + rs * 32 + (r & 3) + 8 * (r >> 2) + 4 * half_;
                const float v = acc[rs][r] + bias[n];
                ((f16*)Yv)[((size_t)(bI * 512 + n)) * 512 + ll] = (f16)v;
            }
        }
    } else {
        const float bv = bias[col0 + wc * 32 + lq];
        #pragma unroll
        for (int rs = 0; rs < 2; ++rs) {
            #pragma unroll
            for (int r = 0; r < 16; ++r) {
                const int row = row0 + wr * 64 + rs * 32 + (r & 3) + 8 * (r >> 2) + 4 * half_;
                const float v = acc[rs][r] + bv;
                const size_t off = (size_t)row * 512 + col0 + wc * 32 + lq;
                if (OUTF32) ((float*)Yv)[off] = v;
                else        ((f16*)Yv)[off]   = (f16)v;
            }
        }
    }
}

__global__ __launch_bounds__(512) void gemm_qk(
    const float* __restrict__ q, const float* __restrict__ k,
    const float* __restrict__ Wq, const float* __restrict__ bq,
    const float* __restrict__ Wk, const float* __restrict__ bk,
    void* __restrict__ Qb, void* __restrict__ Kb)
{
    const float* X = blockIdx.z ? k : q;
    const float* W = blockIdx.z ? Wk : Wq;
    const float* bb = blockIdx.z ? bk : bq;
    void* Y = blockIdx.z ? Kb : Qb;
    gemm_core<0, 0, 0>(X, W, bb, Y);
}

__global__ __launch_bounds__(512) void gemm_v(
    const float* __restrict__ v, const float* __restrict__ Wv,
    const float* __restrict__ bv, void* __restrict__ VT)
{
    gemm_core<0, 0, 1>(v, Wv, bv, VT);
}

__global__ __launch_bounds__(512) void gemm_o(
    const void* __restrict__ X, const float* __restrict__ Wo,
    const float* __restrict__ bo, void* __restrict__ Y)
{
    gemm_core<1, 1, 0>(X, Wo, bo, Y);
}

// ---------------------------------------------------------------------------
// ZERO-LDS MFMA flash attention.  One wave (64 threads) per block; each wave
// owns 32 q-rows of one (b,h) and is fully independent: no LDS, no barriers.
// K fragments = rows of K; V fragments = rows of pre-transposed VT; both
// loaded straight global->VGPR (working set L2-resident, same-(b,h) blocks
// land on the same XCD since gridDim.x=128 => linear id == bh (mod 8)).
// Broadcasts (rescale sc, denominator) via __shfl instead of LDS.
// ---------------------------------------------------------------------------
__global__ __launch_bounds__(64) void attn_kernel(
    const f16* __restrict__ Q, const f16* __restrict__ K,
    const f16* __restrict__ VT, const float* __restrict__ Wg,
    const float* __restrict__ bg, const float* __restrict__ lam1,
    f16* __restrict__ ATT)
{
    const int lane = threadIdx.x;     // 0..63
    const int lq   = lane & 31;
    const int half = lane >> 5;
    const int bh   = blockIdx.x;      // 0..127 ; same bh -> same XCD
    const int b    = bh >> 3;
    const int h    = bh & 7;
    const int q0w  = blockIdx.y * 32;
    const int q    = q0w + lq;

    const float sg  = 1.f / (1.f + __expf(-lam1[0]));
    const float osg = 1.f - sg;

    // Q fragments (B-operand), raw fp16
    f16x8 qh[4];
    {
        const f16* qrow = Q + ((size_t)(b * L_ + q) * DM_ + h * DK_);
        #pragma unroll
        for (int db = 0; db < 4; ++db)
            qh[db] = *(const f16x8*)&qrow[db * 16 + 8 * half];
    }

    // fused gamma: g = q_row . Wg^T + bg ; qp = (|g|+1)^-2  (Wg via L1/L2)
    float A0, A1, qpw;
    {
        float g0 = 0.f, g1 = 0.f;
        #pragma unroll
        for (int db = 0; db < 4; ++db)
            #pragma unroll
            for (int j = 0; j < 8; ++j) {
                const int d = db * 16 + 8 * half + j;
                const float qv = (float)qh[db][j];
                g0 = fmaf(qv, Wg[d], g0);
                g1 = fmaf(qv, Wg[64 + d], g1);
            }
        g0 += __shfl_xor(g0, 32);
        g1 += __shfl_xor(g1, 32);
        g0 += bg[0];
        g1 += bg[1];
        const float t0 = fabsf(g0) + 1.f, t1 = fabsf(g1) + 1.f;
        const float p0 = 1.f / (t0 * t0), p1 = 1.f / (t1 * t1);
        A0 = -NLOG2E_H_ * p0;       // c >= q (triu)
        A1 = -NLOG2E_H_ * p1;       // c <  q (tril)
        float mn = NLOG2E_H_ * fminf(p0, p1);
        #pragma unroll
        for (int off = 1; off < 64; off <<= 1) mn = fminf(mn, __shfl_xor(mn, off));
        qpw = mn;
    }

    f32x16 aS0, aS1, aA0, aA1;
    #pragma unroll
    for (int i = 0; i < 16; ++i) { aS0[i] = 0.f; aS1[i] = 0.f; aA0[i] = 0.f; aA1[i] = 0.f; }
    float m2 = -3.0e38f, sumS = 0.f, sumA = 0.f;

    const f16* Kbase = K  + ((size_t)(b * L_) * DM_ + h * DK_);
    const f16* Vbase = VT + ((size_t)(b * DM_ + h * DK_) * L_);

    for (int t = 0; t < 8; ++t) {
        const int c0 = t * 64;

        // direct global->VGPR fragment loads (16x dwordx4 per lane)
        f16x8 ka[4], kb2[4], vfa[4], vfb[4];
        #pragma unroll
        for (int db = 0; db < 4; ++db) {
            const int dof = db * 16 + 8 * half;
            ka[db]  = *(const f16x8*)&Kbase[(size_t)(c0 + lq) * DM_ + dof];
            kb2[db] = *(const f16x8*)&Kbase[(size_t)(c0 + 32 + lq) * DM_ + dof];
        }
        #pragma unroll
        for (int ks = 0; ks < 4; ++ks) {
            const int coff = c0 + ks * 16 + 8 * half;
            vfa[ks] = *(const f16x8*)&Vbase[(size_t)lq * L_ + coff];
            vfb[ks] = *(const f16x8*)&Vbase[(size_t)(32 + lq) * L_ + coff];
        }

        // S^T = K . Q^T
        f32x16 s2a, s2b;
        #pragma unroll
        for (int i = 0; i < 16; ++i) { s2a[i] = 0.f; s2b[i] = 0.f; }
        #pragma unroll
        for (int db = 0; db < 4; ++db) {
            s2a = __builtin_amdgcn_mfma_f32_32x32x16_f16(ka[db],  qh[db], s2a, 0, 0, 0);
            s2b = __builtin_amdgcn_mfma_f32_32x32x16_f16(kb2[db], qh[db], s2b, 0, 0, 0);
        }

        // online max (lane owns q; halves hold complementary k's)
        float tm = s2a[0];
        #pragma unroll
        for (int i = 1; i < 16; ++i) tm = fmaxf(tm, s2a[i]);
        #pragma unroll
        for (int i = 0; i < 16; ++i) tm = fmaxf(tm, s2b[i]);
        tm = fmaxf(tm, __shfl_xor(tm, 32));
        const float nm = fmaxf(m2, tm);
        const float sc = exp2f((m2 - nm) * LOG2E_);
        m2 = nm;
        sumS *= sc;
        #pragma unroll
        for (int r = 0; r < 16; ++r) {
            const float s_ = __shfl(sc, (r & 3) + 8 * (r >> 2) + 4 * half);
            aS0[r] *= s_;
            aS1[r] *= s_;
        }

        // P: exp, pack, permlane-swap into A-fragments, PV MFMAs
        const float nmL = nm * LOG2E_;
        #pragma unroll
        for (int sub = 0; sub < 2; ++sub) {
            const f32x16& s2 = sub ? s2b : s2a;
            #pragma unroll
            for (int ksl = 0; ksl < 2; ++ksl) {
                const int rb = ksl * 8;
                float p[8];
                #pragma unroll
                for (int rr = 0; rr < 8; ++rr) {
                    p[rr] = exp2f(fmaf(s2[rb + rr], LOG2E_, -nmL));
                    sumS += p[rr];
                }
                union { unsigned u[4]; f16x8 v; } f;
                f.u[0] = pkrtz(p[0], p[1]);
                f.u[1] = pkrtz(p[2], p[3]);
                f.u[2] = pkrtz(p[4], p[5]);
                f.u[3] = pkrtz(p[6], p[7]);
                plswap(f.u[0], f.u[2]);
                plswap(f.u[1], f.u[3]);
                const int ks = sub * 2 + ksl;
                aS0 = __builtin_amdgcn_mfma_f32_32x32x16_f16(f.v, vfa[ks], aS0, 0, 0, 0);
                aS1 = __builtin_amdgcn_mfma_f32_32x32x16_f16(f.v, vfb[ks], aS1, 0, 0, 0);
            }
        }

        // adjacency branch (band-skip far tiles; diagonal tile never skipped)
        int gl_ = q0w - (c0 + 63);
        int gh_ = c0 - (q0w + 31);
        int dmin = gl_ > gh_ ? gl_ : gh_;
        if (dmin < 0) dmin = 0;
        if (qpw * (float)(dmin * dmin) < 40.0f) {
            #pragma unroll
            for (int sub = 0; sub < 2; ++sub) {
                #pragma unroll
                for (int ksl = 0; ksl < 2; ++ksl) {
                    float a[8];
                    #pragma unroll
                    for (int rr = 0; rr < 8; ++rr) {
                        const int kk = (rr & 3) + 8 * (rr >> 2) + 16 * ksl + 4 * half;
                        const int diff = q - (c0 + sub * 32 + kk);
                        const float fd = (float)diff;
                        const float coef = diff > 0 ? A1 : A0;
                        a[rr] = exp2f(coef * fd * fd);
                        sumA += a[rr];
                    }
                    union { unsigned u[4]; f16x8 v; } f;
                    f.u[0] = pkrtz(a[0], a[1]);
                    f.u[1] = pkrtz(a[2], a[3]);
                    f.u[2] = pkrtz(a[4], a[5]);
                    f.u[3] = pkrtz(a[6], a[7]);
                    plswap(f.u[0], f.u[2]);
                    plswap(f.u[1], f.u[3]);
                    const int ks = sub * 2 + ksl;
                    aA0 = __builtin_amdgcn_mfma_f32_32x32x16_f16(f.v, vfa[ks], aA0, 0, 0, 0);
                    aA1 = __builtin_amdgcn_mfma_f32_32x32x16_f16(f.v, vfb[ks], aA1, 0, 0, 0);
                }
            }
        }
    }

    // epilogue: mix branches, degree-normalize, store
    const float St = sumS + __shfl_xor(sumS, 32);
    const float At = sumA + __shfl_xor(sumA, 32);
    const float den = sg * St + osg * At + 1e-9f;
    #pragma unroll
    for (int r = 0; r < 16; ++r) {
        const int row = (r & 3) + 8 * (r >> 2) + 4 * half;
        const float dn = __shfl(den, row);
        const float o0 = (sg * aS0[r] + osg * aA0[r]) / dn;
        const float o1 = (sg * aS1[r] + osg * aA1[r]) / dn;
        const size_t base = (size_t)(b * L_ + q0w + row) * DM_ + h * DK_;
        ATT[base + lq]      = (f16)o0;
        ATT[base + 32 + lq] = (f16)o1;
    }
}

// ---------------------------------------------------------------------------
extern "C" void kernel_launch(void* const* d_in, const int* in_sizes, int n_in,
                              void* d_out, int out_size, void* d_ws, size_t ws_size,
                              hipStream_t stream)
{
    (void)in_sizes; (void)n_in; (void)out_size; (void)ws_size;
    const float* query = (const float*)d_in[0];
    const float* key   = (const float*)d_in[1];
    const float* value = (const float*)d_in[2];
    const float* Wq = (const float*)d_in[3];  const float* bq = (const float*)d_in[4];
    const float* Wk = (const float*)d_in[5];  const float* bk = (const float*)d_in[6];
    const float* Wv = (const float*)d_in[7];  const float* bv = (const float*)d_in[8];
    const float* Wg = (const float*)d_in[9];  const float* bg = (const float*)d_in[10];
    const float* lam1 = (const float*)d_in[11];
    const float* Wo = (const float*)d_in[12]; const float* bo = (const float*)d_in[13];

    f16* ws16 = (f16*)d_ws;
    const size_t NR = (size_t)B_ * L_ * DM_;
    f16* Kb  = ws16;
    f16* VTb = ws16 + NR;
    f16* Qb  = ws16 + 2 * NR;
    f16* ATTb = Qb;   // safe alias: each wave reads exactly the Q cells it later writes

    dim3 gqk(4, 64, 2);
    gemm_qk<<<gqk, 512, 0, stream>>>(query, key, Wq, bq, Wk, bk, Qb, Kb);
    dim3 gg(4, 64);
    gemm_v<<<gg, 512, 0, stream>>>(value, Wv, bv, VTb);

    // one independent wave per block; same-(b,h) blocks share an XCD
    dim3 ga(H_ * B_, L_ / 32);    // (128, 16)
    attn_kernel<<<ga, 64, 0, stream>>>(Qb, Kb, VTb, Wg, bg, lam1, ATTb);

    gemm_o<<<gg, 512, 0, stream>>>(Qb, Wo, bo, (float*)d_out);
}

// Round 7
// 105.414 us; speedup vs baseline: 8.4245x; 1.0246x over previous
//
#include <hip/hip_runtime.h>
#include <hip/hip_fp16.h>
#include <math.h>

#define B_  16
#define H_  8
#define L_  512
#define DM_ 512
#define DK_ 64
#define LOG2E_ 1.44269504088896340736f
#define NLOG2E_H_ 0.72134752044f   // 0.5 * log2(e)

typedef _Float16 f16;
typedef __attribute__((ext_vector_type(2)))  __fp16   fp16v2;
typedef __attribute__((ext_vector_type(8)))  _Float16 f16x8;
typedef __attribute__((ext_vector_type(16))) float f32x16;

__device__ __forceinline__ unsigned pkrtz(float a, float b) {
    union { fp16v2 v; unsigned u; } cv;
    cv.v = __builtin_amdgcn_cvt_pkrtz(a, b);
    return cv.u;
}
// v_permlane32_swap_b32: x[lanes 32..63] <-> y[lanes 0..31]
__device__ __forceinline__ void plswap(unsigned &x, unsigned &y) {
    asm("v_permlane32_swap_b32 %0, %1" : "+v"(x), "+v"(y));
}

// ---------------------------------------------------------------------------
// MFMA fp16 GEMM core:  Y = X[M,512] @ W[512,512]^T + bias
// LDS passed in (32KB) so multiple instantiations in one kernel share it.
// ---------------------------------------------------------------------------
template<int XF16, int OUTF32, int TRANSOUT>
__device__ __forceinline__ void gemm_core(
    const void* __restrict__ Xv, const float* __restrict__ W,
    const float* __restrict__ bias, void* __restrict__ Yv, f16* lds)
{
    f16* Al = lds;
    f16* Bl = lds + 128 * 64;

    const int tid   = threadIdx.x;
    const int w     = tid >> 6;
    const int lane  = tid & 63;
    const int lq    = lane & 31;
    const int half_ = lane >> 5;
    const int wr    = w & 1;
    const int wc    = w >> 1;
    const int row0  = blockIdx.y * 128;
    const int col0  = blockIdx.x * 128;
    const int trow  = tid >> 2;
    const int tseg  = tid & 3;

    f32x16 acc[2];
    #pragma unroll
    for (int rs = 0; rs < 2; ++rs)
        #pragma unroll
        for (int i = 0; i < 16; ++i) acc[rs][i] = 0.f;

    float4 xr[4], wreg[4];
    uint4  xh[2];

    {
        if (XF16) {
            const f16* X = (const f16*)Xv;
            const f16* p = X + (size_t)(row0 + trow) * 512 + tseg * 16;
            xh[0] = *(const uint4*)(p);
            xh[1] = *(const uint4*)(p + 8);
        } else {
            const float* X = (const float*)Xv;
            const float* p = X + (size_t)(row0 + trow) * 512 + tseg * 16;
            xr[0] = *(const float4*)(p);     xr[1] = *(const float4*)(p + 4);
            xr[2] = *(const float4*)(p + 8); xr[3] = *(const float4*)(p + 12);
        }
        const float* q = W + (size_t)(col0 + trow) * 512 + tseg * 16;
        wreg[0] = *(const float4*)(q);     wreg[1] = *(const float4*)(q + 4);
        wreg[2] = *(const float4*)(q + 8); wreg[3] = *(const float4*)(q + 12);
    }

    for (int t = 0; t < 8; ++t) {
        __syncthreads();
        {
            const unsigned base = trow * 128 + tseg * 32;
            const unsigned swz  = (trow & 7) << 4;
            uint4 c0, c1;
            if (XF16) { c0 = xh[0]; c1 = xh[1]; }
            else {
                c0.x = pkrtz(xr[0].x, xr[0].y); c0.y = pkrtz(xr[0].z, xr[0].w);
                c0.z = pkrtz(xr[1].x, xr[1].y); c0.w = pkrtz(xr[1].z, xr[1].w);
                c1.x = pkrtz(xr[2].x, xr[2].y); c1.y = pkrtz(xr[2].z, xr[2].w);
                c1.z = pkrtz(xr[3].x, xr[3].y); c1.w = pkrtz(xr[3].z, xr[3].w);
            }
            *(uint4*)((char*)Al + ((base +  0) ^ swz)) = c0;
            *(uint4*)((char*)Al + ((base + 16) ^ swz)) = c1;
            uint4 d0, d1;
            d0.x = pkrtz(wreg[0].x, wreg[0].y); d0.y = pkrtz(wreg[0].z, wreg[0].w);
            d0.z = pkrtz(wreg[1].x, wreg[1].y); d0.w = pkrtz(wreg[1].z, wreg[1].w);
            d1.x = pkrtz(wreg[2].x, wreg[2].y); d1.y = pkrtz(wreg[2].z, wreg[2].w);
            d1.z = pkrtz(wreg[3].x, wreg[3].y); d1.w = pkrtz(wreg[3].z, wreg[3].w);
            *(uint4*)((char*)Bl + ((base +  0) ^ swz)) = d0;
            *(uint4*)((char*)Bl + ((base + 16) ^ swz)) = d1;
        }
        __syncthreads();

        if (t < 7) {
            const int k0 = (t + 1) * 64;
            if (XF16) {
                const f16* X = (const f16*)Xv;
                const f16* p = X + (size_t)(row0 + trow) * 512 + k0 + tseg * 16;
                xh[0] = *(const uint4*)(p);
                xh[1] = *(const uint4*)(p + 8);
            } else {
                const float* X = (const float*)Xv;
                const float* p = X + (size_t)(row0 + trow) * 512 + k0 + tseg * 16;
                xr[0] = *(const float4*)(p);     xr[1] = *(const float4*)(p + 4);
                xr[2] = *(const float4*)(p + 8); xr[3] = *(const float4*)(p + 12);
            }
            const float* q = W + (size_t)(col0 + trow) * 512 + k0 + tseg * 16;
            wreg[0] = *(const float4*)(q);     wreg[1] = *(const float4*)(q + 4);
            wreg[2] = *(const float4*)(q + 8); wreg[3] = *(const float4*)(q + 12);
        }

        const int ra0 = wr * 64 + lq;
        const int ra1 = wr * 64 + 32 + lq;
        const int rbc = wc * 32 + lq;
        #pragma unroll
        for (int ks = 0; ks < 4; ++ks) {
            const unsigned koff = ks * 32 + half_ * 16;
            f16x8 a0, a1, bf;
            if (TRANSOUT) {
                a0 = *(const f16x8*)((char*)Bl + ((ra0 * 128 + koff) ^ ((ra0 & 7) << 4)));
                a1 = *(const f16x8*)((char*)Bl + ((ra1 * 128 + koff) ^ ((ra1 & 7) << 4)));
                bf = *(const f16x8*)((char*)Al + ((rbc * 128 + koff) ^ ((rbc & 7) << 4)));
            } else {
                a0 = *(const f16x8*)((char*)Al + ((ra0 * 128 + koff) ^ ((ra0 & 7) << 4)));
                a1 = *(const f16x8*)((char*)Al + ((ra1 * 128 + koff) ^ ((ra1 & 7) << 4)));
                bf = *(const f16x8*)((char*)Bl + ((rbc * 128 + koff) ^ ((rbc & 7) << 4)));
            }
            acc[0] = __builtin_amdgcn_mfma_f32_32x32x16_f16(a0, bf, acc[0], 0, 0, 0);
            acc[1] = __builtin_amdgcn_mfma_f32_32x32x16_f16(a1, bf, acc[1], 0, 0, 0);
        }
    }

    if (TRANSOUT) {
        const int lg = row0 + wc * 32 + lq;
        const int bI = lg >> 9, ll = lg & 511;
        #pragma unroll
        for (int rs = 0; rs < 2; ++rs) {
            #pragma unroll
            for (int r = 0; r < 16; ++r) {
                const int n = col0 + wr * 64 + rs * 32 + (r & 3) + 8 * (r >> 2) + 4 * half_;
                const float v = acc[rs][r] + bias[n];
                ((f16*)Yv)[((size_t)(bI * 512 + n)) * 512 + ll] = (f16)v;
            }
        }
    } else {
        const float bv = bias[col0 + wc * 32 + lq];
        #pragma unroll
        for (int rs = 0; rs < 2; ++rs) {
            #pragma unroll
            for (int r = 0; r < 16; ++r) {
                const int row = row0 + wr * 64 + rs * 32 + (r & 3) + 8 * (r >> 2) + 4 * half_;
                const float v = acc[rs][r] + bv;
                const size_t off = (size_t)row * 512 + col0 + wc * 32 + lq;
                if (OUTF32) ((float*)Yv)[off] = v;
                else        ((f16*)Yv)[off]   = (f16)v;
            }
        }
    }
}

// fused Q/K/V projections: z=0 -> Q, z=1 -> K, z=2 -> V^T
__global__ __launch_bounds__(512) void gemm_qkv(
    const float* __restrict__ query, const float* __restrict__ key,
    const float* __restrict__ value,
    const float* __restrict__ Wq, const float* __restrict__ bq,
    const float* __restrict__ Wk, const float* __restrict__ bk,
    const float* __restrict__ Wv, const float* __restrict__ bv,
    void* __restrict__ Qb, void* __restrict__ Kb, void* __restrict__ VT)
{
    __shared__ f16 lds[2 * 128 * 64];
    if (blockIdx.z == 0)      gemm_core<0, 0, 0>(query, Wq, bq, Qb, lds);
    else if (blockIdx.z == 1) gemm_core<0, 0, 0>(key,   Wk, bk, Kb, lds);
    else                      gemm_core<0, 0, 1>(value, Wv, bv, VT, lds);
}

__global__ __launch_bounds__(512) void gemm_o(
    const void* __restrict__ X, const float* __restrict__ Wo,
    const float* __restrict__ bo, void* __restrict__ Y)
{
    __shared__ f16 lds[2 * 128 * 64];
    gemm_core<1, 1, 0>(X, Wo, bo, Y, lds);
}

// ---------------------------------------------------------------------------
// Split-K zero-staging MFMA flash attention.
// Block = 128 threads = 2 waves over the SAME 32 q-rows; wave ws handles KV
// tiles ws*4..ws*4+3 (256 cols each).  Partials merged exactly via one LDS
// dump + barrier with per-row exp(m_i - m) correction.  4096 waves total.
// ---------------------------------------------------------------------------
__global__ __launch_bounds__(128) void attn_kernel(
    const f16* __restrict__ Q, const f16* __restrict__ K,
    const f16* __restrict__ VT, const float* __restrict__ Wg,
    const float* __restrict__ bg, const float* __restrict__ lam1,
    f16* __restrict__ ATT)
{
    __shared__ float Lm[64], Lss[64], Lsa[64];
    __shared__ float Lacc[4][16][64];

    const int tid  = threadIdx.x;
    const int ws   = tid >> 6;        // split-K wave id (0,1)
    const int lane = tid & 63;
    const int lq   = lane & 31;
    const int half = lane >> 5;
    const int bh   = blockIdx.x;      // same bh -> same XCD (128 = 16*NXCD)
    const int b    = bh >> 3;
    const int h    = bh & 7;
    const int q0w  = blockIdx.y * 32;
    const int q    = q0w + lq;

    const float sg  = 1.f / (1.f + __expf(-lam1[0]));
    const float osg = 1.f - sg;

    // Q fragments (B-operand)
    f16x8 qh[4];
    {
        const f16* qrow = Q + ((size_t)(b * L_ + q) * DM_ + h * DK_);
        #pragma unroll
        for (int db = 0; db < 4; ++db)
            qh[db] = *(const f16x8*)&qrow[db * 16 + 8 * half];
    }

    // fused gamma: g = q_row . Wg^T + bg ; qp = (|g|+1)^-2
    float A0, A1, qpw;
    {
        float g0 = 0.f, g1 = 0.f;
        #pragma unroll
        for (int db = 0; db < 4; ++db)
            #pragma unroll
            for (int j = 0; j < 8; ++j) {
                const int d = db * 16 + 8 * half + j;
                const float qv = (float)qh[db][j];
                g0 = fmaf(qv, Wg[d], g0);
                g1 = fmaf(qv, Wg[64 + d], g1);
            }
        g0 += __shfl_xor(g0, 32);
        g1 += __shfl_xor(g1, 32);
        g0 += bg[0];
        g1 += bg[1];
        const float t0 = fabsf(g0) + 1.f, t1 = fabsf(g1) + 1.f;
        const float p0 = 1.f / (t0 * t0), p1 = 1.f / (t1 * t1);
        A0 = -NLOG2E_H_ * p0;       // c >= q (triu)
        A1 = -NLOG2E_H_ * p1;       // c <  q (tril)
        float mn = NLOG2E_H_ * fminf(p0, p1);
        #pragma unroll
        for (int off = 1; off < 64; off <<= 1) mn = fminf(mn, __shfl_xor(mn, off));
        qpw = mn;
    }

    f32x16 aS0, aS1, aA0, aA1;
    #pragma unroll
    for (int i = 0; i < 16; ++i) { aS0[i] = 0.f; aS1[i] = 0.f; aA0[i] = 0.f; aA1[i] = 0.f; }
    float m2 = -3.0e38f, sumS = 0.f, sumA = 0.f;

    const f16* Kbase = K  + ((size_t)(b * L_) * DM_ + h * DK_);
    const f16* Vbase = VT + ((size_t)(b * DM_ + h * DK_) * L_);

    for (int tt = 0; tt < 4; ++tt) {
        const int c0 = (ws * 4 + tt) * 64;

        // direct global->VGPR fragment loads
        f16x8 ka[4], kb2[4], vfa[4], vfb[4];
        #pragma unroll
        for (int db = 0; db < 4; ++db) {
            const int dof = db * 16 + 8 * half;
            ka[db]  = *(const f16x8*)&Kbase[(size_t)(c0 + lq) * DM_ + dof];
            kb2[db] = *(const f16x8*)&Kbase[(size_t)(c0 + 32 + lq) * DM_ + dof];
        }
        #pragma unroll
        for (int ks = 0; ks < 4; ++ks) {
            const int coff = c0 + ks * 16 + 8 * half;
            vfa[ks] = *(const f16x8*)&Vbase[(size_t)lq * L_ + coff];
            vfb[ks] = *(const f16x8*)&Vbase[(size_t)(32 + lq) * L_ + coff];
        }

        // S^T = K . Q^T
        f32x16 s2a, s2b;
        #pragma unroll
        for (int i = 0; i < 16; ++i) { s2a[i] = 0.f; s2b[i] = 0.f; }
        #pragma unroll
        for (int db = 0; db < 4; ++db) {
            s2a = __builtin_amdgcn_mfma_f32_32x32x16_f16(ka[db],  qh[db], s2a, 0, 0, 0);
            s2b = __builtin_amdgcn_mfma_f32_32x32x16_f16(kb2[db], qh[db], s2b, 0, 0, 0);
        }

        // online max with skip-rescale when the wave-wide max is unchanged
        float tm = s2a[0];
        #pragma unroll
        for (int i = 1; i < 16; ++i) tm = fmaxf(tm, s2a[i]);
        #pragma unroll
        for (int i = 0; i < 16; ++i) tm = fmaxf(tm, s2b[i]);
        tm = fmaxf(tm, __shfl_xor(tm, 32));
        if (__any(tm > m2)) {
            const float nm = fmaxf(m2, tm);
            const float sc = exp2f((m2 - nm) * LOG2E_);
            m2 = nm;
            sumS *= sc;
            #pragma unroll
            for (int r = 0; r < 16; ++r) {
                const float s_ = __shfl(sc, (r & 3) + 8 * (r >> 2) + 4 * half);
                aS0[r] *= s_;
                aS1[r] *= s_;
            }
        }

        // P: exp, pack, permlane-swap into A-fragments, PV MFMAs
        const float nmL = m2 * LOG2E_;
        #pragma unroll
        for (int sub = 0; sub < 2; ++sub) {
            const f32x16& s2 = sub ? s2b : s2a;
            #pragma unroll
            for (int ksl = 0; ksl < 2; ++ksl) {
                const int rb = ksl * 8;
                float p[8];
                #pragma unroll
                for (int rr = 0; rr < 8; ++rr) {
                    p[rr] = exp2f(fmaf(s2[rb + rr], LOG2E_, -nmL));
                    sumS += p[rr];
                }
                union { unsigned u[4]; f16x8 v; } f;
                f.u[0] = pkrtz(p[0], p[1]);
                f.u[1] = pkrtz(p[2], p[3]);
                f.u[2] = pkrtz(p[4], p[5]);
                f.u[3] = pkrtz(p[6], p[7]);
                plswap(f.u[0], f.u[2]);
                plswap(f.u[1], f.u[3]);
                const int ks = sub * 2 + ksl;
                aS0 = __builtin_amdgcn_mfma_f32_32x32x16_f16(f.v, vfa[ks], aS0, 0, 0, 0);
                aS1 = __builtin_amdgcn_mfma_f32_32x32x16_f16(f.v, vfb[ks], aS1, 0, 0, 0);
            }
        }

        // adjacency branch (band-skip far tiles; diagonal tile never skipped)
        int gl_ = q0w - (c0 + 63);
        int gh_ = c0 - (q0w + 31);
        int dmin = gl_ > gh_ ? gl_ : gh_;
        if (dmin < 0) dmin = 0;
        if (qpw * (float)(dmin * dmin) < 40.0f) {
            #pragma unroll
            for (int sub = 0; sub < 2; ++sub) {
                #pragma unroll
                for (int ksl = 0; ksl < 2; ++ksl) {
                    float a[8];
                    #pragma unroll
                    for (int rr = 0; rr < 8; ++rr) {
                        const int kk = (rr & 3) + 8 * (rr >> 2) + 16 * ksl + 4 * half;
                        const int diff = q - (c0 + sub * 32 + kk);
                        const float fd = (float)diff;
                        const float coef = diff > 0 ? A1 : A0;
                        a[rr] = exp2f(coef * fd * fd);
                        sumA += a[rr];
                    }
                    union { unsigned u[4]; f16x8 v; } f;
                    f.u[0] = pkrtz(a[0], a[1]);
                    f.u[1] = pkrtz(a[2], a[3]);
                    f.u[2] = pkrtz(a[4], a[5]);
                    f.u[3] = pkrtz(a[6], a[7]);
                    plswap(f.u[0], f.u[2]);
                    plswap(f.u[1], f.u[3]);
                    const int ks = sub * 2 + ksl;
                    aA0 = __builtin_amdgcn_mfma_f32_32x32x16_f16(f.v, vfa[ks], aA0, 0, 0, 0);
                    aA1 = __builtin_amdgcn_mfma_f32_32x32x16_f16(f.v, vfb[ks], aA1, 0, 0, 0);
                }
            }
        }
    }

    // split-K merge: wave1 dumps partials; wave0 combines + writes output.
    if (ws == 1) {
        Lm[lane]  = m2;
        Lss[lane] = sumS;
        Lsa[lane] = sumA;
        #pragma unroll
        for (int r = 0; r < 16; ++r) {
            Lacc[0][r][lane] = aS0[r];
            Lacc[1][r][lane] = aS1[r];
            Lacc[2][r][lane] = aA0[r];
            Lacc[3][r][lane] = aA1[r];
        }
    }
    __syncthreads();
    if (ws == 0) {
        const float m2p = Lm[lane];
        const float nm  = fmaxf(m2, m2p);
        const float e0  = exp2f((m2  - nm) * LOG2E_);
        const float e1  = exp2f((m2p - nm) * LOG2E_);
        const float ssm = sumS * e0 + Lss[lane] * e1;
        const float sam = sumA + Lsa[lane];
        const float St  = ssm + __shfl_xor(ssm, 32);
        const float At  = sam + __shfl_xor(sam, 32);
        const float den = sg * St + osg * At + 1e-9f;
        #pragma unroll
        for (int r = 0; r < 16; ++r) {
            const int row = (r & 3) + 8 * (r >> 2) + 4 * half;
            const float dn  = __shfl(den, row);
            const float e0r = __shfl(e0, row);
            const float e1r = __shfl(e1, row);
            const float o0 = (sg * (aS0[r] * e0r + Lacc[0][r][lane] * e1r)
                            + osg * (aA0[r] + Lacc[2][r][lane])) / dn;
            const float o1 = (sg * (aS1[r] * e0r + Lacc[1][r][lane] * e1r)
                            + osg * (aA1[r] + Lacc[3][r][lane])) / dn;
            const size_t base = (size_t)(b * L_ + q0w + row) * DM_ + h * DK_;
            ATT[base + lq]      = (f16)o0;
            ATT[base + 32 + lq] = (f16)o1;
        }
    }
}

// ---------------------------------------------------------------------------
extern "C" void kernel_launch(void* const* d_in, const int* in_sizes, int n_in,
                              void* d_out, int out_size, void* d_ws, size_t ws_size,
                              hipStream_t stream)
{
    (void)in_sizes; (void)n_in; (void)out_size; (void)ws_size;
    const float* query = (const float*)d_in[0];
    const float* key   = (const float*)d_in[1];
    const float* value = (const float*)d_in[2];
    const float* Wq = (const float*)d_in[3];  const float* bq = (const float*)d_in[4];
    const float* Wk = (const float*)d_in[5];  const float* bk = (const float*)d_in[6];
    const float* Wv = (const float*)d_in[7];  const float* bv = (const float*)d_in[8];
    const float* Wg = (const float*)d_in[9];  const float* bg = (const float*)d_in[10];
    const float* lam1 = (const float*)d_in[11];
    const float* Wo = (const float*)d_in[12]; const float* bo = (const float*)d_in[13];

    f16* ws16 = (f16*)d_ws;
    const size_t NR = (size_t)B_ * L_ * DM_;
    f16* Kb  = ws16;
    f16* VTb = ws16 + NR;
    f16* Qb  = ws16 + 2 * NR;
    f16* ATTb = Qb;   // safe alias: each block reads exactly the Q cells it later writes

    dim3 gqkv(4, 64, 3);
    gemm_qkv<<<gqkv, 512, 0, stream>>>(query, key, value, Wq, bq, Wk, bk, Wv, bv,
                                       Qb, Kb, VTb);

    dim3 ga(H_ * B_, L_ / 32);    // (128, 16), 128 threads = 2 split-K waves
    attn_kernel<<<ga, 128, 0, stream>>>(Qb, Kb, VTb, Wg, bg, lam1, ATTb);

    dim3 gg(4, 64);
    gemm_o<<<gg, 512, 0, stream>>>(Qb, Wo, bo, (float*)d_out);
}